// Round 2
// baseline (370.937 us; speedup 1.0000x reference)
//
#include <hip/hip_runtime.h>
#include <hip/hip_bf16.h>
#include <math.h>

#define S_LEN 4096
#define HID   1280
#define NH    16
#define HD    80
#define HDP   96
#define N3    3840
#define KVB   64

typedef __bf16 bf16_t;
typedef __bf16 bf16x8 __attribute__((ext_vector_type(8)));
typedef float  f32x4  __attribute__((ext_vector_type(4)));

__device__ inline void gload_lds16(const bf16_t* g, const bf16_t* lds_base){
  __builtin_amdgcn_global_load_lds((const __attribute__((address_space(1))) void*)g,
                                   (__attribute__((address_space(3))) void*)lds_base,
                                   16, 0, 0);
}

// ---------------- prep kernels ----------------

__global__ void k_f2bf(const float* __restrict__ in, bf16_t* __restrict__ out, int n){
  int i = blockIdx.x * blockDim.x + threadIdx.x;
  int stride = gridDim.x * blockDim.x;
  for (; i < n; i += stride) out[i] = (bf16_t)in[i];
}

// out[n*K + k] = (bf16) in[k*N + n]
__global__ void k_transpose_bf(const float* __restrict__ in, bf16_t* __restrict__ out, int K, int N){
  size_t i = (size_t)blockIdx.x * blockDim.x + threadIdx.x;
  size_t total = (size_t)K * N;
  size_t stride = (size_t)gridDim.x * blockDim.x;
  for (; i < total; i += stride){
    size_t n = i / (size_t)K, k = i % (size_t)K;
    out[i] = (bf16_t)in[k * (size_t)N + n];
  }
}

__global__ void k_seg(const int* __restrict__ cu, int* __restrict__ seg,
                      int* __restrict__ rlo, int* __restrict__ rhi){
  int s = blockIdx.x * blockDim.x + threadIdx.x;
  if (s >= S_LEN) return;
  int c = 0;
  #pragma unroll
  for (int j = 0; j < 9; ++j) c += (cu[j] <= s) ? 1 : 0;
  seg[s] = c;
  rlo[s] = cu[c - 1];
  rhi[s] = cu[c];
}

// ---------------- GEMM: C[m][n] = sum_k A[m][k]*Bt[n][k] + bias[n] ----------------
// 128x128 tile, BK=32, 4 waves, global_load_lds staging (m97 structure).
template<bool OUT_BF16>
__global__ __launch_bounds__(256) void k_gemm(const bf16_t* __restrict__ A, const bf16_t* __restrict__ Bt,
                                              const float* __restrict__ bias, void* __restrict__ outp,
                                              int M, int N, int K){
  __shared__ bf16_t sA[128 * 32];
  __shared__ bf16_t sB[128 * 32];
  const int tid  = threadIdx.x;
  const int lane = tid & 63;
  const int wave = tid >> 6;
  const int wr = wave >> 1, wc = wave & 1;
  const int g = lane >> 4, l16 = lane & 15;
  const int m0 = blockIdx.y * 128, n0 = blockIdx.x * 128;

  f32x4 acc[4][4] = {};

  // staging: 8 chunks of 1KB per tile; wave w issues chunks 2w, 2w+1.
  // chunk c: rows [16c,16c+16), lane l -> row 16c + (l>>2), elem-off (l&3)*8.
  // LDS dest = tile_base + c*1024B (+ lane*16 by HW) == row-major [128][32] bf16.
  const int c0 = 2 * wave, c1 = 2 * wave + 1;
  const int r0 = c0 * 16 + (lane >> 2), r1 = c1 * 16 + (lane >> 2);
  const int koff = (lane & 3) * 8;

  for (int k0 = 0; k0 < K; k0 += 32){
    __syncthreads();   // all waves done reading LDS from previous iter
    gload_lds16(A  + (size_t)(m0 + r0) * K + k0 + koff, sA + c0 * 512);
    gload_lds16(A  + (size_t)(m0 + r1) * K + k0 + koff, sA + c1 * 512);
    gload_lds16(Bt + (size_t)(n0 + r0) * K + k0 + koff, sB + c0 * 512);
    gload_lds16(Bt + (size_t)(n0 + r1) * K + k0 + koff, sB + c1 * 512);
    __syncthreads();   // drains vmcnt -> tile ready
    bf16x8 af[4], bfv[4];
    #pragma unroll
    for (int mi = 0; mi < 4; ++mi) af[mi]  = *(const bf16x8*)(sA + (wr * 64 + mi * 16 + l16) * 32 + g * 8);
    #pragma unroll
    for (int ni = 0; ni < 4; ++ni) bfv[ni] = *(const bf16x8*)(sB + (wc * 64 + ni * 16 + l16) * 32 + g * 8);
    #pragma unroll
    for (int mi = 0; mi < 4; ++mi)
      #pragma unroll
      for (int ni = 0; ni < 4; ++ni)
        acc[mi][ni] = __builtin_amdgcn_mfma_f32_16x16x32_bf16(af[mi], bfv[ni], acc[mi][ni], 0, 0, 0);
  }

  #pragma unroll
  for (int ni = 0; ni < 4; ++ni){
    const int col = n0 + wc * 64 + ni * 16 + l16;
    const float bv = bias[col];
    #pragma unroll
    for (int mi = 0; mi < 4; ++mi){
      const int row = m0 + wr * 64 + mi * 16 + g * 4;
      #pragma unroll
      for (int r = 0; r < 4; ++r){
        float v = acc[mi][ni][r] + bv;
        if (OUT_BF16) ((bf16_t*)outp)[(size_t)(row + r) * N + col] = (bf16_t)v;
        else          ((float*) outp)[(size_t)(row + r) * N + col] = v;
      }
    }
  }
}

// ---------------- RoPE + head-major repack (q pre-scaled by 1/sqrt(HD)) ----------------
__global__ void k_rope(const bf16_t* __restrict__ qkv, const float* __restrict__ rope,
                       bf16_t* __restrict__ q_t, bf16_t* __restrict__ k_t){
  const int s = blockIdx.x;
  const int tid = threadIdx.x;
  const size_t base = (size_t)s * N3;
  const float SCALE = 0.11180339887498949f; // 1/sqrt(80)
  for (int i = tid; i < HID; i += 256){
    const int h = i / HD, d = i % HD;
    const int dm = (d < 40) ? d : d - 40;
    float sn, cs;
    sincosf(rope[s * 40 + dm], &sn, &cs);
    const int i2 = (d < 40) ? i + 40 : i - 40;
    float qv = (float)qkv[base + i];
    float kv = (float)qkv[base + HID + i];
    float q2 = (float)qkv[base + i2];
    float k2 = (float)qkv[base + HID + i2];
    float sg = (d < 40) ? -1.f : 1.f;
    size_t o = ((size_t)h * S_LEN + s) * HDP + d;
    q_t[o] = (bf16_t)((qv * cs + sg * q2 * sn) * SCALE);
    k_t[o] = (bf16_t)(kv * cs + sg * k2 * sn);
  }
  for (int i = tid; i < NH * 16; i += 256){
    const int h = i >> 4, d = HD + (i & 15);
    size_t o = ((size_t)h * S_LEN + s) * HDP + d;
    q_t[o] = (bf16_t)0.f;
    k_t[o] = (bf16_t)0.f;
  }
}

// ---------------- V transpose: v_T[h][d][s] = v[s][h][d] ----------------
__global__ __launch_bounds__(256) void k_vtrans(const bf16_t* __restrict__ qkv, bf16_t* __restrict__ v_T){
  const int h  = blockIdx.z;
  const int d0 = blockIdx.y * 16;
  const int s0 = blockIdx.x * 64;
  __shared__ bf16_t tile[64][17];
  const int tid = threadIdx.x;
  const int dl = tid & 15, sl = tid >> 4;
  #pragma unroll
  for (int p = 0; p < 4; ++p){
    int s = s0 + p * 16 + sl;
    tile[p * 16 + sl][dl] = qkv[(size_t)s * N3 + 2 * HID + h * HD + d0 + dl];
  }
  __syncthreads();
  const int s2 = tid & 63, d2 = tid >> 6;
  #pragma unroll
  for (int p = 0; p < 4; ++p){
    int d = p * 4 + d2;
    v_T[((size_t)h * HDP + d0 + d) * S_LEN + s0 + s2] = tile[s2][d];
  }
}

// ---------------- flash attention, block-diagonal mask ----------------
// 256-thread blocks = 4 independent waves; wave owns 16 q-rows, loops its own
// segment span in KVB=64 steps. No block barriers (per-wave sP, lgkmcnt-ordered).
__global__ __launch_bounds__(256) void k_attn(const bf16_t* __restrict__ q_t, const bf16_t* __restrict__ k_t,
                                              const bf16_t* __restrict__ v_T, const int* __restrict__ seg,
                                              const int* __restrict__ rlo, const int* __restrict__ rhi,
                                              bf16_t* __restrict__ attn){
  const int h = blockIdx.y;
  const int tid = threadIdx.x;
  const int wave = tid >> 6, lane = tid & 63;
  const int q0 = (blockIdx.x * 4 + wave) * 16;
  const int g = lane >> 4, l16 = lane & 15;
  const size_t hq = (size_t)h * S_LEN;

  __shared__ bf16_t sP[4][16 * KVB];
  bf16_t* myP = (bf16_t*)sP[wave];

  bf16x8 qf[3];
  #pragma unroll
  for (int c = 0; c < 3; ++c)
    qf[c] = *(const bf16x8*)(q_t + (hq + q0 + l16) * HDP + c * 32 + g * 8);

  int sq[4];
  #pragma unroll
  for (int r = 0; r < 4; ++r) sq[r] = seg[q0 + g * 4 + r];
  const int lo = rlo[q0], hi = rhi[q0 + 15];

  float m_run[4] = {-1e30f, -1e30f, -1e30f, -1e30f};
  float l_run[4] = {0.f, 0.f, 0.f, 0.f};
  f32x4 acc[5] = {};

  for (int kv0 = (lo & ~(KVB - 1)); kv0 < hi; kv0 += KVB){
    f32x4 sc[4];
    int sk[4];
    #pragma unroll
    for (int j = 0; j < 4; ++j){
      f32x4 t = {0.f, 0.f, 0.f, 0.f};
      #pragma unroll
      for (int c = 0; c < 3; ++c){
        bf16x8 kf = *(const bf16x8*)(k_t + (hq + kv0 + j * 16 + l16) * HDP + c * 32 + g * 8);
        t = __builtin_amdgcn_mfma_f32_16x16x32_bf16(qf[c], kf, t, 0, 0, 0);
      }
      sc[j] = t;
      sk[j] = seg[kv0 + j * 16 + l16];
    }
    // D layout: col(kv)=l16, row(q)=g*4+r. q pre-scaled, so sc is the logit.
    float p[4][4], fr[4];
    #pragma unroll
    for (int r = 0; r < 4; ++r){
      float mx = -1e30f;
      #pragma unroll
      for (int j = 0; j < 4; ++j){
        float a = (sq[r] == sk[j]) ? sc[j][r] : -1e30f;
        p[j][r] = a;
        mx = fmaxf(mx, a);
      }
      mx = fmaxf(mx, __shfl_xor(mx, 1, 16));
      mx = fmaxf(mx, __shfl_xor(mx, 2, 16));
      mx = fmaxf(mx, __shfl_xor(mx, 4, 16));
      mx = fmaxf(mx, __shfl_xor(mx, 8, 16));
      float mn = fmaxf(m_run[r], mx);
      fr[r] = __expf(m_run[r] - mn);     // exp(0)=1 when unchanged / all-masked
      m_run[r] = mn;
      float s2 = 0.f;
      #pragma unroll
      for (int j = 0; j < 4; ++j){
        float pe = (p[j][r] > -1e29f) ? __expf(p[j][r] - mn) : 0.f;
        p[j][r] = pe;
        s2 += pe;
      }
      s2 += __shfl_xor(s2, 1, 16);
      s2 += __shfl_xor(s2, 2, 16);
      s2 += __shfl_xor(s2, 4, 16);
      s2 += __shfl_xor(s2, 8, 16);
      l_run[r] = l_run[r] * fr[r] + s2;
    }
    #pragma unroll
    for (int ni = 0; ni < 5; ++ni)
      #pragma unroll
      for (int r = 0; r < 4; ++r)
        acc[ni][r] *= fr[r];
    // P (row=q=g*4+r, col=kv=j*16+l16) -> per-wave LDS -> A-frags (row=l16, k=ks*32+g*8+e)
    #pragma unroll
    for (int j = 0; j < 4; ++j)
      #pragma unroll
      for (int r = 0; r < 4; ++r)
        myP[(g * 4 + r) * KVB + j * 16 + l16] = (bf16_t)p[j][r];
    bf16x8 pa0 = *(const bf16x8*)(myP + l16 * KVB + g * 8);
    bf16x8 pa1 = *(const bf16x8*)(myP + l16 * KVB + 32 + g * 8);
    #pragma unroll
    for (int ni = 0; ni < 5; ++ni){
      const bf16_t* vrow = v_T + ((size_t)h * HDP + ni * 16 + l16) * S_LEN + kv0;
      bf16x8 vf0 = *(const bf16x8*)(vrow + g * 8);
      bf16x8 vf1 = *(const bf16x8*)(vrow + 32 + g * 8);
      acc[ni] = __builtin_amdgcn_mfma_f32_16x16x32_bf16(pa0, vf0, acc[ni], 0, 0, 0);
      acc[ni] = __builtin_amdgcn_mfma_f32_16x16x32_bf16(pa1, vf1, acc[ni], 0, 0, 0);
    }
  }
  #pragma unroll
  for (int ni = 0; ni < 5; ++ni){
    #pragma unroll
    for (int r = 0; r < 4; ++r){
      float o = acc[ni][r] / l_run[r];
      attn[(size_t)(q0 + g * 4 + r) * HID + h * HD + ni * 16 + l16] = (bf16_t)o;
    }
  }
}

// ---------------- launch ----------------

extern "C" void kernel_launch(void* const* d_in, const int* in_sizes, int n_in,
                              void* d_out, int out_size, void* d_ws, size_t ws_size,
                              hipStream_t stream){
  const float* x    = (const float*)d_in[0];
  const float* rope = (const float*)d_in[1];
  const int*   cu   = (const int*)  d_in[2];
  const float* wqkv = (const float*)d_in[3];
  const float* bqkv = (const float*)d_in[4];
  const float* wo   = (const float*)d_in[5];
  const float* bo   = (const float*)d_in[6];
  float* out = (float*)d_out;

  char* ws = (char*)d_ws;
  size_t off = 0;
  auto alloc = [&](size_t bytes) -> void* {
    void* p = ws + off;
    off += (bytes + 255) & ~(size_t)255;
    return p;
  };
  bf16_t* x_bf   = (bf16_t*)alloc((size_t)S_LEN * HID * 2);
  bf16_t* w_t    = (bf16_t*)alloc((size_t)N3 * HID * 2);
  bf16_t* wo_t   = (bf16_t*)alloc((size_t)HID * HID * 2);
  bf16_t* qkv_bf = (bf16_t*)alloc((size_t)S_LEN * N3 * 2);
  bf16_t* q_t    = (bf16_t*)alloc((size_t)NH * S_LEN * HDP * 2);
  bf16_t* k_t    = (bf16_t*)alloc((size_t)NH * S_LEN * HDP * 2);
  bf16_t* v_T    = (bf16_t*)alloc((size_t)NH * HDP * S_LEN * 2);
  int* seg = (int*)alloc(S_LEN * 4);
  int* rlo = (int*)alloc(S_LEN * 4);
  int* rhi = (int*)alloc(S_LEN * 4);
  bf16_t* attn_bf = x_bf;  // alias: x_bf dead after QKV GEMM

  k_f2bf<<<2048, 256, 0, stream>>>(x, x_bf, S_LEN * HID);
  k_transpose_bf<<<2048, 256, 0, stream>>>(wqkv, w_t, HID, N3);
  k_transpose_bf<<<2048, 256, 0, stream>>>(wo, wo_t, HID, HID);
  k_seg<<<16, 256, 0, stream>>>(cu, seg, rlo, rhi);

  k_gemm<true><<<dim3(N3 / 128, S_LEN / 128), 256, 0, stream>>>(x_bf, w_t, bqkv, qkv_bf, S_LEN, N3, HID);

  k_rope<<<S_LEN, 256, 0, stream>>>(qkv_bf, rope, q_t, k_t);
  k_vtrans<<<dim3(S_LEN / 64, 5, NH), 256, 0, stream>>>(qkv_bf, v_T);

  k_attn<<<dim3(S_LEN / 64, NH), 256, 0, stream>>>(q_t, k_t, v_T, seg, rlo, rhi, attn_bf);

  k_gemm<false><<<dim3(HID / 128, S_LEN / 128), 256, 0, stream>>>(attn_bf, wo_t, bo, out, S_LEN, HID, HID);
}

// Round 3
// 319.468 us; speedup vs baseline: 1.1611x; 1.1611x over previous
//
#include <hip/hip_runtime.h>
#include <hip/hip_bf16.h>
#include <math.h>

#define S_LEN 4096
#define HID   1280
#define NH    16
#define HD    80
#define HDP   96
#define N3    3840
#define KVB   64

typedef __bf16 bf16_t;
typedef __bf16 bf16x4 __attribute__((ext_vector_type(4)));
typedef __bf16 bf16x8 __attribute__((ext_vector_type(8)));
typedef float  f32x4  __attribute__((ext_vector_type(4)));

__device__ inline void gload_lds16(const bf16_t* g, const bf16_t* lds_base){
  __builtin_amdgcn_global_load_lds((const __attribute__((address_space(1))) void*)g,
                                   (__attribute__((address_space(3))) void*)lds_base,
                                   16, 0, 0);
}

// ---------------- prep kernels ----------------

__global__ void k_f2bf(const float* __restrict__ in, bf16_t* __restrict__ out, int n4){
  int i = blockIdx.x * blockDim.x + threadIdx.x;
  int stride = gridDim.x * blockDim.x;
  for (; i < n4; i += stride){
    float4 v = ((const float4*)in)[i];
    bf16x4 o;
    o[0] = (bf16_t)v.x; o[1] = (bf16_t)v.y; o[2] = (bf16_t)v.z; o[3] = (bf16_t)v.w;
    ((bf16x4*)out)[i] = o;
  }
}

// in: K x N f32 row-major -> out: N x K bf16 row-major, 64x64 LDS tiles
__global__ __launch_bounds__(256) void k_transpose_bf(const float* __restrict__ in, bf16_t* __restrict__ out,
                                                      int K, int N){
  __shared__ bf16_t tile[64][65];
  const int tid = threadIdx.x;
  const int n0 = blockIdx.x * 64, k0 = blockIdx.y * 64;
  const int ln = tid & 63, w = tid >> 6;
  #pragma unroll
  for (int p = 0; p < 16; ++p){
    int k = w + p * 4;
    tile[k][ln] = (bf16_t)in[(size_t)(k0 + k) * N + n0 + ln];
  }
  __syncthreads();
  const int lk = tid & 63;
  #pragma unroll
  for (int p = 0; p < 16; ++p){
    int n = w + p * 4;
    out[(size_t)(n0 + n) * K + k0 + lk] = tile[lk][n];
  }
}

__global__ void k_seg(const int* __restrict__ cu, int* __restrict__ seg,
                      int* __restrict__ rlo, int* __restrict__ rhi){
  int s = blockIdx.x * blockDim.x + threadIdx.x;
  if (s >= S_LEN) return;
  int c = 0;
  #pragma unroll
  for (int j = 0; j < 9; ++j) c += (cu[j] <= s) ? 1 : 0;
  seg[s] = c;
  rlo[s] = cu[c - 1];
  rhi[s] = cu[c];
}

// ---------------- GEMM: C[m][n] = sum_k A[m][k]*Bt[n][k] + bias[n] ----------------
template<bool OUT_BF16>
__global__ __launch_bounds__(256) void k_gemm(const bf16_t* __restrict__ A, const bf16_t* __restrict__ Bt,
                                              const float* __restrict__ bias, void* __restrict__ outp,
                                              int M, int N, int K){
  __shared__ bf16_t sA[128 * 32];
  __shared__ bf16_t sB[128 * 32];
  const int tid  = threadIdx.x;
  const int lane = tid & 63;
  const int wave = tid >> 6;
  const int wr = wave >> 1, wc = wave & 1;
  const int g = lane >> 4, l16 = lane & 15;
  const int m0 = blockIdx.y * 128, n0 = blockIdx.x * 128;

  f32x4 acc[4][4] = {};

  const int c0 = 2 * wave, c1 = 2 * wave + 1;
  const int r0 = c0 * 16 + (lane >> 2), r1 = c1 * 16 + (lane >> 2);
  const int koff = (lane & 3) * 8;

  for (int k0 = 0; k0 < K; k0 += 32){
    __syncthreads();
    gload_lds16(A  + (size_t)(m0 + r0) * K + k0 + koff, sA + c0 * 512);
    gload_lds16(A  + (size_t)(m0 + r1) * K + k0 + koff, sA + c1 * 512);
    gload_lds16(Bt + (size_t)(n0 + r0) * K + k0 + koff, sB + c0 * 512);
    gload_lds16(Bt + (size_t)(n0 + r1) * K + k0 + koff, sB + c1 * 512);
    __syncthreads();
    bf16x8 af[4], bfv[4];
    #pragma unroll
    for (int mi = 0; mi < 4; ++mi) af[mi]  = *(const bf16x8*)(sA + (wr * 64 + mi * 16 + l16) * 32 + g * 8);
    #pragma unroll
    for (int ni = 0; ni < 4; ++ni) bfv[ni] = *(const bf16x8*)(sB + (wc * 64 + ni * 16 + l16) * 32 + g * 8);
    #pragma unroll
    for (int mi = 0; mi < 4; ++mi)
      #pragma unroll
      for (int ni = 0; ni < 4; ++ni)
        acc[mi][ni] = __builtin_amdgcn_mfma_f32_16x16x32_bf16(af[mi], bfv[ni], acc[mi][ni], 0, 0, 0);
  }

  #pragma unroll
  for (int ni = 0; ni < 4; ++ni){
    const int col = n0 + wc * 64 + ni * 16 + l16;
    const float bv = bias[col];
    #pragma unroll
    for (int mi = 0; mi < 4; ++mi){
      const int row = m0 + wr * 64 + mi * 16 + g * 4;
      #pragma unroll
      for (int r = 0; r < 4; ++r){
        float v = acc[mi][ni][r] + bv;
        if (OUT_BF16) ((bf16_t*)outp)[(size_t)(row + r) * N + col] = (bf16_t)v;
        else          ((float*) outp)[(size_t)(row + r) * N + col] = v;
      }
    }
  }
}

// ---------------- RoPE: shared trig per position, (d, d+40) pair processing ----------------
__global__ void k_rope(const bf16_t* __restrict__ qkv, const float* __restrict__ rope,
                       bf16_t* __restrict__ q_t, bf16_t* __restrict__ k_t){
  const int s = blockIdx.x;
  const int tid = threadIdx.x;
  __shared__ float cs_s[40], sn_s[40];
  if (tid < 40){
    float sn, cs;
    sincosf(rope[s * 40 + tid], &sn, &cs);
    cs_s[tid] = cs; sn_s[tid] = sn;
  }
  __syncthreads();
  const size_t base = (size_t)s * N3;
  const float SCALE = 0.11180339887498949f; // 1/sqrt(80)
  for (int t = tid; t < NH * 40; t += 256){
    const int h = t / 40, dm = t % 40;
    const float cs = cs_s[dm], sn = sn_s[dm];
    const int i = h * HD + dm;
    float q1 = (float)qkv[base + i];
    float q2 = (float)qkv[base + i + 40];
    float k1 = (float)qkv[base + HID + i];
    float k2 = (float)qkv[base + HID + i + 40];
    size_t o = ((size_t)h * S_LEN + s) * HDP + dm;
    q_t[o]      = (bf16_t)((q1 * cs - q2 * sn) * SCALE);
    q_t[o + 40] = (bf16_t)((q2 * cs + q1 * sn) * SCALE);
    k_t[o]      = (bf16_t)(k1 * cs - k2 * sn);
    k_t[o + 40] = (bf16_t)(k2 * cs + k1 * sn);
  }
  for (int t = tid; t < NH * 16; t += 256){
    const int h = t >> 4, d = HD + (t & 15);
    size_t o = ((size_t)h * S_LEN + s) * HDP + d;
    q_t[o] = (bf16_t)0.f;
    k_t[o] = (bf16_t)0.f;
  }
}

// ---------------- V transpose: v_T[h][d][s] = v[s][h][d] ----------------
__global__ __launch_bounds__(256) void k_vtrans(const bf16_t* __restrict__ qkv, bf16_t* __restrict__ v_T){
  const int h  = blockIdx.z;
  const int d0 = blockIdx.y * 16;
  const int s0 = blockIdx.x * 64;
  __shared__ bf16_t tile[64][17];
  const int tid = threadIdx.x;
  const int dl = tid & 15, sl = tid >> 4;
  #pragma unroll
  for (int p = 0; p < 4; ++p){
    int s = s0 + p * 16 + sl;
    tile[p * 16 + sl][dl] = qkv[(size_t)s * N3 + 2 * HID + h * HD + d0 + dl];
  }
  __syncthreads();
  const int s2 = tid & 63, d2 = tid >> 6;
  #pragma unroll
  for (int p = 0; p < 4; ++p){
    int d = p * 4 + d2;
    v_T[((size_t)h * HDP + d0 + d) * S_LEN + s0 + s2] = tile[s2][d];
  }
}

// ---------------- flash attention, swapped-operand MFMA (lane-local softmax) ----------------
// 4 independent waves/block, wave owns 16 q-rows (q = l16). Swapped QK^T: D col=q,
// row=kv -> 16 lane-local scores per 64-key tile. Softmax: 15 in-reg ops + 2 shfl.
// Swapped PV: acc col=q -> rescale/divide lane-local. P^T via XOR-swizzled LDS
// (4x ds_write_b64 + 2x ds_read_b128/step, ~2-way conflicts).
__global__ __launch_bounds__(256) void k_attn(const bf16_t* __restrict__ q_t, const bf16_t* __restrict__ k_t,
                                              const bf16_t* __restrict__ v_T, const int* __restrict__ rlo,
                                              const int* __restrict__ rhi, bf16_t* __restrict__ attn){
  const int h = blockIdx.y;
  const int tid = threadIdx.x;
  const int wave = tid >> 6, lane = tid & 63;
  const int q0 = (blockIdx.x * 4 + wave) * 16;
  const int g = lane >> 4, l16 = lane & 15;
  const size_t hq = (size_t)h * S_LEN;

  __shared__ bf16_t sP[4][16 * KVB];
  bf16_t* myP = (bf16_t*)sP[wave];
  const int swz = (l16 & 7) << 3;

  bf16x8 qf[3];
  #pragma unroll
  for (int c = 0; c < 3; ++c)
    qf[c] = *(const bf16x8*)(q_t + (hq + q0 + l16) * HDP + c * 32 + g * 8);

  const int my_lo = rlo[q0 + l16], my_hi = rhi[q0 + l16];
  const int lo = rlo[q0], hi = rhi[q0 + 15];

  float m_run = -1e30f, l_run = 0.f;
  f32x4 acc[5] = {};

  for (int kv0 = (lo & ~(KVB - 1)); kv0 < hi; kv0 += KVB){
    f32x4 sc[4];
    #pragma unroll
    for (int j = 0; j < 4; ++j){
      f32x4 t = {0.f, 0.f, 0.f, 0.f};
      #pragma unroll
      for (int c = 0; c < 3; ++c){
        bf16x8 kf = *(const bf16x8*)(k_t + (hq + kv0 + j * 16 + l16) * HDP + c * 32 + g * 8);
        t = __builtin_amdgcn_mfma_f32_16x16x32_bf16(kf, qf[c], t, 0, 0, 0);  // swapped
      }
      sc[j] = t;
    }
    // lane holds scores for q=q0+l16 at kv = kv0 + j*16 + g*4 + r
    float p[4][4];
    float mx = -1e30f;
    #pragma unroll
    for (int j = 0; j < 4; ++j)
      #pragma unroll
      for (int r = 0; r < 4; ++r){
        int kvi = kv0 + j * 16 + g * 4 + r;
        bool ok = (kvi >= my_lo) && (kvi < my_hi);
        float sv = ok ? sc[j][r] : -1e30f;
        p[j][r] = sv;
        mx = fmaxf(mx, sv);
      }
    mx = fmaxf(mx, __shfl_xor(mx, 16));
    mx = fmaxf(mx, __shfl_xor(mx, 32));
    float mn = fmaxf(m_run, mx);
    float fr = __expf(m_run - mn);   // exp(0)=1 when unchanged / all-masked
    m_run = mn;
    float sum = 0.f;
    #pragma unroll
    for (int j = 0; j < 4; ++j)
      #pragma unroll
      for (int r = 0; r < 4; ++r){
        float pe = (p[j][r] > -1e29f) ? __expf(p[j][r] - mn) : 0.f;
        p[j][r] = pe;
        sum += pe;
      }
    sum += __shfl_xor(sum, 16);
    sum += __shfl_xor(sum, 32);
    l_run = l_run * fr + sum;
    #pragma unroll
    for (int ni = 0; ni < 5; ++ni)
      #pragma unroll
      for (int r = 0; r < 4; ++r)
        acc[ni][r] *= fr;
    // P^T to LDS: row q=l16, col kv^swz (swizzle bits>=3 keeps 4-elem groups contiguous)
    #pragma unroll
    for (int j = 0; j < 4; ++j){
      bf16x4 pv;
      #pragma unroll
      for (int r = 0; r < 4; ++r) pv[r] = (bf16_t)p[j][r];
      *(bf16x4*)(myP + l16 * KVB + ((j * 16 + g * 4) ^ swz)) = pv;
    }
    bf16x8 pa0 = *(const bf16x8*)(myP + l16 * KVB + ((g * 8) ^ swz));
    bf16x8 pa1 = *(const bf16x8*)(myP + l16 * KVB + ((32 + g * 8) ^ swz));
    #pragma unroll
    for (int ni = 0; ni < 5; ++ni){
      const bf16_t* vrow = v_T + ((size_t)h * HDP + ni * 16 + l16) * S_LEN + kv0;
      bf16x8 vf0 = *(const bf16x8*)(vrow + g * 8);
      bf16x8 vf1 = *(const bf16x8*)(vrow + 32 + g * 8);
      acc[ni] = __builtin_amdgcn_mfma_f32_16x16x32_bf16(vf0, pa0, acc[ni], 0, 0, 0);  // swapped
      acc[ni] = __builtin_amdgcn_mfma_f32_16x16x32_bf16(vf1, pa1, acc[ni], 0, 0, 0);
    }
  }
  // acc: row = d = ni*16 + g*4 + r, col = q = l16 (lane-local l_run)
  const float inv = 1.f / l_run;
  #pragma unroll
  for (int ni = 0; ni < 5; ++ni)
    #pragma unroll
    for (int r = 0; r < 4; ++r)
      attn[(size_t)(q0 + l16) * HID + h * HD + ni * 16 + g * 4 + r] = (bf16_t)(acc[ni][r] * inv);
}

// ---------------- launch ----------------

extern "C" void kernel_launch(void* const* d_in, const int* in_sizes, int n_in,
                              void* d_out, int out_size, void* d_ws, size_t ws_size,
                              hipStream_t stream){
  const float* x    = (const float*)d_in[0];
  const float* rope = (const float*)d_in[1];
  const int*   cu   = (const int*)  d_in[2];
  const float* wqkv = (const float*)d_in[3];
  const float* bqkv = (const float*)d_in[4];
  const float* wo   = (const float*)d_in[5];
  const float* bo   = (const float*)d_in[6];
  float* out = (float*)d_out;

  char* ws = (char*)d_ws;
  size_t off = 0;
  auto alloc = [&](size_t bytes) -> void* {
    void* p = ws + off;
    off += (bytes + 255) & ~(size_t)255;
    return p;
  };
  bf16_t* x_bf   = (bf16_t*)alloc((size_t)S_LEN * HID * 2);
  bf16_t* w_t    = (bf16_t*)alloc((size_t)N3 * HID * 2);
  bf16_t* wo_t   = (bf16_t*)alloc((size_t)HID * HID * 2);
  bf16_t* qkv_bf = (bf16_t*)alloc((size_t)S_LEN * N3 * 2);
  bf16_t* q_t    = (bf16_t*)alloc((size_t)NH * S_LEN * HDP * 2);
  bf16_t* k_t    = (bf16_t*)alloc((size_t)NH * S_LEN * HDP * 2);
  bf16_t* v_T    = (bf16_t*)alloc((size_t)NH * HDP * S_LEN * 2);
  int* seg = (int*)alloc(S_LEN * 4);
  int* rlo = (int*)alloc(S_LEN * 4);
  int* rhi = (int*)alloc(S_LEN * 4);
  bf16_t* attn_bf = x_bf;  // alias: x_bf dead after QKV GEMM

  k_f2bf<<<1024, 256, 0, stream>>>(x, x_bf, S_LEN * HID / 4);
  k_transpose_bf<<<dim3(N3 / 64, HID / 64), 256, 0, stream>>>(wqkv, w_t, HID, N3);
  k_transpose_bf<<<dim3(HID / 64, HID / 64), 256, 0, stream>>>(wo, wo_t, HID, HID);
  k_seg<<<16, 256, 0, stream>>>(cu, seg, rlo, rhi);

  k_gemm<true><<<dim3(N3 / 128, S_LEN / 128), 256, 0, stream>>>(x_bf, w_t, bqkv, qkv_bf, S_LEN, N3, HID);

  k_rope<<<S_LEN, 256, 0, stream>>>(qkv_bf, rope, q_t, k_t);
  k_vtrans<<<dim3(S_LEN / 64, 5, NH), 256, 0, stream>>>(qkv_bf, v_T);

  k_attn<<<dim3(S_LEN / 64, NH), 256, 0, stream>>>(q_t, k_t, v_T, rlo, rhi, attn_bf);

  k_gemm<false><<<dim3(HID / 128, S_LEN / 128), 256, 0, stream>>>(attn_bf, wo_t, bo, out, S_LEN, HID, HID);
}

// Round 4
// 209.208 us; speedup vs baseline: 1.7731x; 1.5270x over previous
//
#include <hip/hip_runtime.h>
#include <hip/hip_bf16.h>
#include <math.h>

#define S_LEN 4096
#define HID   1280
#define NH    16
#define HD    80
#define HDP   96
#define N3    3840
#define KVB   64

typedef __bf16 bf16_t;
typedef __bf16 bf16x4 __attribute__((ext_vector_type(4)));
typedef __bf16 bf16x8 __attribute__((ext_vector_type(8)));
typedef float  f32x4  __attribute__((ext_vector_type(4)));

__device__ inline void gload_lds16(const bf16_t* g, const bf16_t* lds_base){
  __builtin_amdgcn_global_load_lds((const __attribute__((address_space(1))) void*)g,
                                   (__attribute__((address_space(3))) void*)lds_base,
                                   16, 0, 0);
}

// ---------------- prep kernels ----------------

__global__ void k_f2bf(const float* __restrict__ in, bf16_t* __restrict__ out, int n4){
  int i = blockIdx.x * blockDim.x + threadIdx.x;
  int stride = gridDim.x * blockDim.x;
  for (; i < n4; i += stride){
    float4 v = ((const float4*)in)[i];
    bf16x4 o;
    o[0] = (bf16_t)v.x; o[1] = (bf16_t)v.y; o[2] = (bf16_t)v.z; o[3] = (bf16_t)v.w;
    ((bf16x4*)out)[i] = o;
  }
}

// in: K x N f32 row-major -> out: N x K bf16 row-major, 64x64 LDS tiles
__global__ __launch_bounds__(256) void k_transpose_bf(const float* __restrict__ in, bf16_t* __restrict__ out,
                                                      int K, int N){
  __shared__ bf16_t tile[64][65];
  const int tid = threadIdx.x;
  const int n0 = blockIdx.x * 64, k0 = blockIdx.y * 64;
  const int ln = tid & 63, w = tid >> 6;
  #pragma unroll
  for (int p = 0; p < 16; ++p){
    int k = w + p * 4;
    tile[k][ln] = (bf16_t)in[(size_t)(k0 + k) * N + n0 + ln];
  }
  __syncthreads();
  const int lk = tid & 63;
  #pragma unroll
  for (int p = 0; p < 16; ++p){
    int n = w + p * 4;
    out[(size_t)(n0 + n) * K + k0 + lk] = tile[lk][n];
  }
}

__global__ void k_seg(const int* __restrict__ cu, int* __restrict__ seg,
                      int* __restrict__ rlo, int* __restrict__ rhi){
  int s = blockIdx.x * blockDim.x + threadIdx.x;
  if (s >= S_LEN) return;
  int c = 0;
  #pragma unroll
  for (int j = 0; j < 9; ++j) c += (cu[j] <= s) ? 1 : 0;
  seg[s] = c;
  rlo[s] = cu[c - 1];
  rhi[s] = cu[c];
}

// ---------------- GEMM: C[m][n] = sum_k A[m][k]*Bt[n][k] + bias[n] ----------------
template<bool OUT_BF16>
__global__ __launch_bounds__(256) void k_gemm(const bf16_t* __restrict__ A, const bf16_t* __restrict__ Bt,
                                              const float* __restrict__ bias, void* __restrict__ outp,
                                              int M, int N, int K){
  __shared__ bf16_t sA[128 * 32];
  __shared__ bf16_t sB[128 * 32];
  const int tid  = threadIdx.x;
  const int lane = tid & 63;
  const int wave = tid >> 6;
  const int wr = wave >> 1, wc = wave & 1;
  const int g = lane >> 4, l16 = lane & 15;
  const int m0 = blockIdx.y * 128, n0 = blockIdx.x * 128;

  f32x4 acc[4][4] = {};

  const int c0 = 2 * wave, c1 = 2 * wave + 1;
  const int r0 = c0 * 16 + (lane >> 2), r1 = c1 * 16 + (lane >> 2);
  const int koff = (lane & 3) * 8;

  for (int k0 = 0; k0 < K; k0 += 32){
    __syncthreads();
    gload_lds16(A  + (size_t)(m0 + r0) * K + k0 + koff, sA + c0 * 512);
    gload_lds16(A  + (size_t)(m0 + r1) * K + k0 + koff, sA + c1 * 512);
    gload_lds16(Bt + (size_t)(n0 + r0) * K + k0 + koff, sB + c0 * 512);
    gload_lds16(Bt + (size_t)(n0 + r1) * K + k0 + koff, sB + c1 * 512);
    __syncthreads();
    bf16x8 af[4], bfv[4];
    #pragma unroll
    for (int mi = 0; mi < 4; ++mi) af[mi]  = *(const bf16x8*)(sA + (wr * 64 + mi * 16 + l16) * 32 + g * 8);
    #pragma unroll
    for (int ni = 0; ni < 4; ++ni) bfv[ni] = *(const bf16x8*)(sB + (wc * 64 + ni * 16 + l16) * 32 + g * 8);
    #pragma unroll
    for (int mi = 0; mi < 4; ++mi)
      #pragma unroll
      for (int ni = 0; ni < 4; ++ni)
        acc[mi][ni] = __builtin_amdgcn_mfma_f32_16x16x32_bf16(af[mi], bfv[ni], acc[mi][ni], 0, 0, 0);
  }

  #pragma unroll
  for (int ni = 0; ni < 4; ++ni){
    const int col = n0 + wc * 64 + ni * 16 + l16;
    const float bv = bias[col];
    #pragma unroll
    for (int mi = 0; mi < 4; ++mi){
      const int row = m0 + wr * 64 + mi * 16 + g * 4;
      #pragma unroll
      for (int r = 0; r < 4; ++r){
        float v = acc[mi][ni][r] + bv;
        if (OUT_BF16) ((bf16_t*)outp)[(size_t)(row + r) * N + col] = (bf16_t)v;
        else          ((float*) outp)[(size_t)(row + r) * N + col] = v;
      }
    }
  }
}

// ---------------- RoPE: shared trig per position, (d, d+40) pair processing ----------------
__global__ void k_rope(const bf16_t* __restrict__ qkv, const float* __restrict__ rope,
                       bf16_t* __restrict__ q_t, bf16_t* __restrict__ k_t){
  const int s = blockIdx.x;
  const int tid = threadIdx.x;
  __shared__ float cs_s[40], sn_s[40];
  if (tid < 40){
    float sn, cs;
    sincosf(rope[s * 40 + tid], &sn, &cs);
    cs_s[tid] = cs; sn_s[tid] = sn;
  }
  __syncthreads();
  const size_t base = (size_t)s * N3;
  const float SCALE = 0.11180339887498949f; // 1/sqrt(80)
  for (int t = tid; t < NH * 40; t += 256){
    const int h = t / 40, dm = t % 40;
    const float cs = cs_s[dm], sn = sn_s[dm];
    const int i = h * HD + dm;
    float q1 = (float)qkv[base + i];
    float q2 = (float)qkv[base + i + 40];
    float k1 = (float)qkv[base + HID + i];
    float k2 = (float)qkv[base + HID + i + 40];
    size_t o = ((size_t)h * S_LEN + s) * HDP + dm;
    q_t[o]      = (bf16_t)((q1 * cs - q2 * sn) * SCALE);
    q_t[o + 40] = (bf16_t)((q2 * cs + q1 * sn) * SCALE);
    k_t[o]      = (bf16_t)(k1 * cs - k2 * sn);
    k_t[o + 40] = (bf16_t)(k2 * cs + k1 * sn);
  }
  for (int t = tid; t < NH * 16; t += 256){
    const int h = t >> 4, d = HD + (t & 15);
    size_t o = ((size_t)h * S_LEN + s) * HDP + d;
    q_t[o] = (bf16_t)0.f;
    k_t[o] = (bf16_t)0.f;
  }
}

// ---------------- V transpose: v_T[h][d][s] = v[s][h][d] ----------------
__global__ __launch_bounds__(256) void k_vtrans(const bf16_t* __restrict__ qkv, bf16_t* __restrict__ v_T){
  const int h  = blockIdx.z;
  const int d0 = blockIdx.y * 16;
  const int s0 = blockIdx.x * 64;
  __shared__ bf16_t tile[64][17];
  const int tid = threadIdx.x;
  const int dl = tid & 15, sl = tid >> 4;
  #pragma unroll
  for (int p = 0; p < 4; ++p){
    int s = s0 + p * 16 + sl;
    tile[p * 16 + sl][dl] = qkv[(size_t)s * N3 + 2 * HID + h * HD + d0 + dl];
  }
  __syncthreads();
  const int s2 = tid & 63, d2 = tid >> 6;
  #pragma unroll
  for (int p = 0; p < 4; ++p){
    int d = p * 4 + d2;
    v_T[((size_t)h * HDP + d0 + d) * S_LEN + s0 + s2] = tile[s2][d];
  }
}

// ---------------- flash attention: cooperative LDS-staged K/V, swapped MFMA ----------------
// Block = 4 waves = 64 q-rows of one head. Per 64-key tile: K staged [64][208B-pad]
// (2-way-free reads), V staged [80][128B] with XOR-swizzled SOURCE (rule #21).
// Wave w computes q rows [qb*64+16w, +16); per-lane seg-range masking; lane-local softmax.
// XCD-affinity: 2 heads per XCD for L2 residency.
__global__ __launch_bounds__(256) void k_attn(const bf16_t* __restrict__ q_t, const bf16_t* __restrict__ k_t,
                                              const bf16_t* __restrict__ v_T, const int* __restrict__ rlo,
                                              const int* __restrict__ rhi, bf16_t* __restrict__ attn){
  // LDS: [0,13312) K tile 64 rows x 208B; [13312,23552) V tile 80 rows x 128B;
  //      [23552,31744) per-wave P buffers (4 x 2048B)
  __shared__ bf16_t sLds[15872];

  const int b = blockIdx.x;
  const int xcd = b & 7, bi = b >> 3;
  const int h  = xcd * 2 + (bi & 1);
  const int qb = bi >> 1;

  const int tid = threadIdx.x;
  const int wave = tid >> 6, lane = tid & 63;
  const int g = lane >> 4, l16 = lane & 15;
  const int q0 = qb * 64 + wave * 16;
  const size_t hq = (size_t)h * S_LEN;
  const bf16_t* vbase = v_T + (size_t)h * HDP * S_LEN;

  bf16_t* myP = sLds + 11776 + wave * 1024;
  const int swz = (l16 & 7) << 3;

  // staging chunk precompute: 23 chunks of 1024B; wave w takes c = w, w+4, ...
  // K chunk c<13: LDS byte p=c*1024+lane*16 -> row=p/208, slot=(p%208)/16;
  //   src elem off (from k_t + (hq+kv0)*96): row*96 + slot*8  (slot 12 = 16B overrun, benign)
  // V chunk cv=c-13: p=cv*1024+lane*16 -> row=cv*8+lane/8, slot=lane&7, scol=slot^(row&7);
  //   src elem off (from vbase + kv0): row*S_LEN + scol*8
  int soff[6];
  #pragma unroll
  for (int i = 0; i < 6; ++i){
    int c = wave + 4 * i;
    if (c < 13){
      int p = c * 1024 + lane * 16;
      int row = p / 208, slot = (p % 208) >> 4;
      soff[i] = row * 96 + slot * 8;
    } else if (c < 23){
      int cv = c - 13;
      int row = cv * 8 + (lane >> 3);
      int scol = (lane & 7) ^ (row & 7);
      soff[i] = row * S_LEN + scol * 8;
    } else soff[i] = 0;
  }

  bf16x8 qf[3];
  #pragma unroll
  for (int c = 0; c < 3; ++c)
    qf[c] = *(const bf16x8*)(q_t + (hq + q0 + l16) * HDP + c * 32 + g * 8);

  const int my_lo = rlo[q0 + l16], my_hi = rhi[q0 + l16];
  const int w_lo = rlo[q0], w_hi = rhi[q0 + 15];
  const int lo_blk = rlo[qb * 64] & ~(KVB - 1);
  const int hi_blk = rhi[qb * 64 + 63];

  float m_run = -1e30f, l_run = 0.f;
  f32x4 acc[5] = {};

  for (int kv0 = lo_blk; kv0 < hi_blk; kv0 += KVB){
    __syncthreads();   // previous tile's LDS reads complete
    const bf16_t* kbase = k_t + (hq + kv0) * HDP;
    #pragma unroll
    for (int i = 0; i < 6; ++i){
      int c = wave + 4 * i;
      if (c < 13)      gload_lds16(kbase + soff[i], sLds + c * 512);
      else if (c < 23) gload_lds16(vbase + kv0 + soff[i], sLds + c * 512);
    }
    __syncthreads();   // vmcnt drained -> tile ready

    if (kv0 + KVB > w_lo && kv0 < w_hi){
      f32x4 sc[4];
      #pragma unroll
      for (int j = 0; j < 4; ++j){
        f32x4 t = {0.f, 0.f, 0.f, 0.f};
        #pragma unroll
        for (int c = 0; c < 3; ++c){
          // K[kv=j*16+l16][d=c*32+g*8..]: row stride 104 elems (208B), slot 4c+g
          bf16x8 kf = *(const bf16x8*)(sLds + (j * 16 + l16) * 104 + (4 * c + g) * 8);
          t = __builtin_amdgcn_mfma_f32_16x16x32_bf16(kf, qf[c], t, 0, 0, 0);  // swapped
        }
        sc[j] = t;
      }
      // lane holds scores for q=q0+l16 at kv = kv0 + j*16 + g*4 + r
      float p[4][4];
      float mx = -1e30f;
      #pragma unroll
      for (int j = 0; j < 4; ++j)
        #pragma unroll
        for (int r = 0; r < 4; ++r){
          int kvi = kv0 + j * 16 + g * 4 + r;
          bool ok = (kvi >= my_lo) && (kvi < my_hi);
          float sv = ok ? sc[j][r] : -1e30f;
          p[j][r] = sv;
          mx = fmaxf(mx, sv);
        }
      mx = fmaxf(mx, __shfl_xor(mx, 16));
      mx = fmaxf(mx, __shfl_xor(mx, 32));
      float mn = fmaxf(m_run, mx);
      float fr = __expf(m_run - mn);
      m_run = mn;
      float sum = 0.f;
      #pragma unroll
      for (int j = 0; j < 4; ++j)
        #pragma unroll
        for (int r = 0; r < 4; ++r){
          float pe = (p[j][r] > -1e29f) ? __expf(p[j][r] - mn) : 0.f;
          p[j][r] = pe;
          sum += pe;
        }
      sum += __shfl_xor(sum, 16);
      sum += __shfl_xor(sum, 32);
      l_run = l_run * fr + sum;
      #pragma unroll
      for (int ni = 0; ni < 5; ++ni)
        #pragma unroll
        for (int r = 0; r < 4; ++r)
          acc[ni][r] *= fr;
      // P^T via per-wave swizzled LDS
      #pragma unroll
      for (int j = 0; j < 4; ++j){
        bf16x4 pv;
        #pragma unroll
        for (int r = 0; r < 4; ++r) pv[r] = (bf16_t)p[j][r];
        *(bf16x4*)(myP + l16 * KVB + ((j * 16 + g * 4) ^ swz)) = pv;
      }
      bf16x8 pa0 = *(const bf16x8*)(myP + l16 * KVB + ((g * 8) ^ swz));
      bf16x8 pa1 = *(const bf16x8*)(myP + l16 * KVB + ((32 + g * 8) ^ swz));
      #pragma unroll
      for (int ni = 0; ni < 5; ++ni){
        // V[d=ni*16+l16][kv slot 4j+g], swizzled slot
        const int d = ni * 16 + l16;
        bf16x8 vf0 = *(const bf16x8*)(sLds + 6656 + d * 64 + ((g) ^ (d & 7)) * 8);
        bf16x8 vf1 = *(const bf16x8*)(sLds + 6656 + d * 64 + ((4 + g) ^ (d & 7)) * 8);
        acc[ni] = __builtin_amdgcn_mfma_f32_16x16x32_bf16(vf0, pa0, acc[ni], 0, 0, 0);  // swapped
        acc[ni] = __builtin_amdgcn_mfma_f32_16x16x32_bf16(vf1, pa1, acc[ni], 0, 0, 0);
      }
    }
  }
  // acc: row = d = ni*16 + g*4 + r, col = q = l16
  const float inv = 1.f / l_run;
  #pragma unroll
  for (int ni = 0; ni < 5; ++ni)
    #pragma unroll
    for (int r = 0; r < 4; ++r)
      attn[(size_t)(q0 + l16) * HID + h * HD + ni * 16 + g * 4 + r] = (bf16_t)(acc[ni][r] * inv);
}

// ---------------- launch ----------------

extern "C" void kernel_launch(void* const* d_in, const int* in_sizes, int n_in,
                              void* d_out, int out_size, void* d_ws, size_t ws_size,
                              hipStream_t stream){
  const float* x    = (const float*)d_in[0];
  const float* rope = (const float*)d_in[1];
  const int*   cu   = (const int*)  d_in[2];
  const float* wqkv = (const float*)d_in[3];
  const float* bqkv = (const float*)d_in[4];
  const float* wo   = (const float*)d_in[5];
  const float* bo   = (const float*)d_in[6];
  float* out = (float*)d_out;

  char* ws = (char*)d_ws;
  size_t off = 0;
  auto alloc = [&](size_t bytes) -> void* {
    void* p = ws + off;
    off += (bytes + 255) & ~(size_t)255;
    return p;
  };
  bf16_t* x_bf   = (bf16_t*)alloc((size_t)S_LEN * HID * 2);
  bf16_t* w_t    = (bf16_t*)alloc((size_t)N3 * HID * 2);
  bf16_t* wo_t   = (bf16_t*)alloc((size_t)HID * HID * 2);
  bf16_t* qkv_bf = (bf16_t*)alloc((size_t)S_LEN * N3 * 2);
  bf16_t* q_t    = (bf16_t*)alloc((size_t)NH * S_LEN * HDP * 2);
  bf16_t* k_t    = (bf16_t*)alloc((size_t)NH * S_LEN * HDP * 2);
  bf16_t* v_T    = (bf16_t*)alloc((size_t)NH * HDP * S_LEN * 2);
  int* seg = (int*)alloc(S_LEN * 4);
  int* rlo = (int*)alloc(S_LEN * 4);
  int* rhi = (int*)alloc(S_LEN * 4);
  bf16_t* attn_bf = x_bf;  // alias: x_bf dead after QKV GEMM

  k_f2bf<<<1024, 256, 0, stream>>>(x, x_bf, S_LEN * HID / 4);
  k_transpose_bf<<<dim3(N3 / 64, HID / 64), 256, 0, stream>>>(wqkv, w_t, HID, N3);
  k_transpose_bf<<<dim3(HID / 64, HID / 64), 256, 0, stream>>>(wo, wo_t, HID, HID);
  k_seg<<<16, 256, 0, stream>>>(cu, seg, rlo, rhi);

  k_gemm<true><<<dim3(N3 / 128, S_LEN / 128), 256, 0, stream>>>(x_bf, w_t, bqkv, qkv_bf, S_LEN, N3, HID);

  k_rope<<<S_LEN, 256, 0, stream>>>(qkv_bf, rope, q_t, k_t);
  k_vtrans<<<dim3(S_LEN / 64, 5, NH), 256, 0, stream>>>(qkv_bf, v_T);

  k_attn<<<1024, 256, 0, stream>>>(q_t, k_t, v_T, rlo, rhi, attn_bf);

  k_gemm<false><<<dim3(HID / 128, S_LEN / 128), 256, 0, stream>>>(attn_bf, wo_t, bo, out, S_LEN, HID, HID);
}

// Round 5
// 184.870 us; speedup vs baseline: 2.0065x; 1.1317x over previous
//
#include <hip/hip_runtime.h>
#include <hip/hip_bf16.h>
#include <math.h>

#define S_LEN 4096
#define HID   1280
#define NH    16
#define HD    80
#define HDP   96
#define N3    3840
#define KVB   64

typedef __bf16 bf16_t;
typedef __bf16 bf16x4 __attribute__((ext_vector_type(4)));
typedef __bf16 bf16x8 __attribute__((ext_vector_type(8)));
typedef float  f32x4  __attribute__((ext_vector_type(4)));

__device__ inline void gload_lds16(const bf16_t* g, const bf16_t* lds_base){
  __builtin_amdgcn_global_load_lds((const __attribute__((address_space(1))) void*)g,
                                   (__attribute__((address_space(3))) void*)lds_base,
                                   16, 0, 0);
}

// ---------------- prep kernels ----------------

__global__ void k_f2bf(const float* __restrict__ in, bf16_t* __restrict__ out, int n4){
  int i = blockIdx.x * blockDim.x + threadIdx.x;
  int stride = gridDim.x * blockDim.x;
  for (; i < n4; i += stride){
    float4 v = ((const float4*)in)[i];
    bf16x4 o;
    o[0] = (bf16_t)v.x; o[1] = (bf16_t)v.y; o[2] = (bf16_t)v.z; o[3] = (bf16_t)v.w;
    ((bf16x4*)out)[i] = o;
  }
}

// in: K x N f32 row-major -> out: N x K bf16 row-major, 64x64 LDS tiles
__global__ __launch_bounds__(256) void k_transpose_bf(const float* __restrict__ in, bf16_t* __restrict__ out,
                                                      int K, int N){
  __shared__ bf16_t tile[64][65];
  const int tid = threadIdx.x;
  const int n0 = blockIdx.x * 64, k0 = blockIdx.y * 64;
  const int ln = tid & 63, w = tid >> 6;
  #pragma unroll
  for (int p = 0; p < 16; ++p){
    int k = w + p * 4;
    tile[k][ln] = (bf16_t)in[(size_t)(k0 + k) * N + n0 + ln];
  }
  __syncthreads();
  const int lk = tid & 63;
  #pragma unroll
  for (int p = 0; p < 16; ++p){
    int n = w + p * 4;
    out[(size_t)(n0 + n) * K + k0 + lk] = tile[lk][n];
  }
}

__global__ void k_seg(const int* __restrict__ cu, int* __restrict__ seg,
                      int* __restrict__ rlo, int* __restrict__ rhi){
  int s = blockIdx.x * blockDim.x + threadIdx.x;
  if (s >= S_LEN) return;
  int c = 0;
  #pragma unroll
  for (int j = 0; j < 9; ++j) c += (cu[j] <= s) ? 1 : 0;
  seg[s] = c;
  rlo[s] = cu[c - 1];
  rhi[s] = cu[c];
}

// ---------------- 256x256 8-wave deep-pipelined GEMM (QKV): C = A*Bt^T + bias ----------------
// BK=32, double-buffered 64KB LDS, T2 slot-swizzle, raw barriers + counted vmcnt (T4),
// 2 phases/tile with setprio MFMA clusters (T3/T5). bf16 out.
__global__ __launch_bounds__(512, 2) void k_gemm256(const bf16_t* __restrict__ A, const bf16_t* __restrict__ Bt,
                                                    const float* __restrict__ bias, bf16_t* __restrict__ outp,
                                                    int M, int N, int K, int nbn){
  // LDS elems: buf b: A at b*16384, B at b*16384+8192. Each tile region: 128 phys rows
  // (2 logical rows folded) x 64 elems; granule (16B) slot swizzled: ((row&1)*4+slot)^((row>>1)&7).
  __shared__ bf16_t lds[32768];
  const int tid = threadIdx.x;
  const int wv = tid >> 6, lane = tid & 63;
  const int waveM = wv >> 2, waveN = wv & 3;
  const int g = lane >> 4, l16 = lane & 15;

  const int cpx = gridDim.x >> 3;
  const int bswz = ((int)blockIdx.x & 7) * cpx + ((int)blockIdx.x >> 3);
  const int m0 = (bswz / nbn) * 256, n0 = (bswz % nbn) * 256;

  // staging decode: thread's chunks c = wv + 8i (A region and B region each, i=0,1).
  // chunk c = 8 phys rows; lane l -> phys row c*8 + (l>>3); stored granule (l&7);
  // source granule = (l&7) ^ (l>>3)  -> logical row = prow*2 + (src>>2), slot = src&3.
  int srow[2], scol[2];
  #pragma unroll
  for (int i = 0; i < 2; ++i){
    int c = wv + 8 * i;
    int prow = c * 8 + (lane >> 3);
    int inner = (lane & 7) ^ (lane >> 3);
    srow[i] = prow * 2 + (inner >> 2);
    scol[i] = (inner & 3) * 8;
  }

  // reader fragment offsets (elems within region)
  const int swzh = (l16 >> 1) & 7;
  const int rcol = ((((l16 & 1) << 2) + g) ^ swzh) * 8;
  int aoff[8], boff[4];
  #pragma unroll
  for (int mi = 0; mi < 8; ++mi)
    aoff[mi] = (waveM * 64 + mi * 8 + (l16 >> 1)) * 64 + rcol;
  #pragma unroll
  for (int ni = 0; ni < 4; ++ni)
    boff[ni] = (waveN * 32 + ni * 8 + (l16 >> 1)) * 64 + rcol;

  f32x4 acc[8][4] = {};
  const int NT = K / 32;

  auto stage = [&](int t, int bb){
    const int kc = t * 32;
    #pragma unroll
    for (int i = 0; i < 2; ++i)
      gload_lds16(A + (size_t)(m0 + srow[i]) * K + kc + scol[i], lds + bb * 16384 + (wv + 8 * i) * 512);
    #pragma unroll
    for (int i = 0; i < 2; ++i)
      gload_lds16(Bt + (size_t)(n0 + srow[i]) * K + kc + scol[i], lds + bb * 16384 + 8192 + (wv + 8 * i) * 512);
  };

  stage(0, 0);
  int cur = 0;
  for (int t = 0; t < NT; ++t){
    if (t + 1 < NT){
      stage(t + 1, cur ^ 1);
      asm volatile("s_waitcnt vmcnt(4)" ::: "memory");  // tile t's 4 loads done; t+1's stay in flight
    } else {
      asm volatile("s_waitcnt vmcnt(0)" ::: "memory");
    }
    asm volatile("s_barrier" ::: "memory");

    const bf16_t* Ab = lds + cur * 16384;
    const bf16_t* Bb = Ab + 8192;
    bf16x8 bfv[4], af[4];
    #pragma unroll
    for (int ni = 0; ni < 4; ++ni) bfv[ni] = *(const bf16x8*)(Bb + boff[ni]);
    #pragma unroll
    for (int mi = 0; mi < 4; ++mi) af[mi] = *(const bf16x8*)(Ab + aoff[mi]);
    __builtin_amdgcn_s_setprio(1);
    #pragma unroll
    for (int mi = 0; mi < 4; ++mi)
      #pragma unroll
      for (int ni = 0; ni < 4; ++ni)
        acc[mi][ni] = __builtin_amdgcn_mfma_f32_16x16x32_bf16(af[mi], bfv[ni], acc[mi][ni], 0, 0, 0);
    __builtin_amdgcn_s_setprio(0);
    asm volatile("s_barrier" ::: "memory");

    #pragma unroll
    for (int mi = 0; mi < 4; ++mi) af[mi] = *(const bf16x8*)(Ab + aoff[4 + mi]);
    __builtin_amdgcn_s_setprio(1);
    #pragma unroll
    for (int mi = 0; mi < 4; ++mi)
      #pragma unroll
      for (int ni = 0; ni < 4; ++ni)
        acc[4 + mi][ni] = __builtin_amdgcn_mfma_f32_16x16x32_bf16(af[mi], bfv[ni], acc[4 + mi][ni], 0, 0, 0);
    __builtin_amdgcn_s_setprio(0);
    asm volatile("s_barrier" ::: "memory");  // all reads of buf[cur] done before next-iter overwrite
    cur ^= 1;
  }

  #pragma unroll
  for (int ni = 0; ni < 4; ++ni){
    const int col = n0 + waveN * 64 + ni * 16 + l16;
    const float bv = bias[col];
    #pragma unroll
    for (int mi = 0; mi < 8; ++mi){
      const int row = m0 + waveM * 128 + mi * 16 + g * 4;
      #pragma unroll
      for (int r = 0; r < 4; ++r)
        outp[(size_t)(row + r) * N + col] = (bf16_t)(acc[mi][ni][r] + bv);
    }
  }
}

// ---------------- 128x128 GEMM (proj): C = A*Bt^T + bias, f32 out ----------------
__global__ __launch_bounds__(256) void k_gemm(const bf16_t* __restrict__ A, const bf16_t* __restrict__ Bt,
                                              const float* __restrict__ bias, float* __restrict__ outp,
                                              int M, int N, int K){
  __shared__ bf16_t sA[128 * 32];
  __shared__ bf16_t sB[128 * 32];
  const int tid  = threadIdx.x;
  const int lane = tid & 63;
  const int wave = tid >> 6;
  const int wr = wave >> 1, wc = wave & 1;
  const int g = lane >> 4, l16 = lane & 15;
  const int m0 = blockIdx.y * 128, n0 = blockIdx.x * 128;

  f32x4 acc[4][4] = {};

  const int c0 = 2 * wave, c1 = 2 * wave + 1;
  const int r0 = c0 * 16 + (lane >> 2), r1 = c1 * 16 + (lane >> 2);
  const int koff = (lane & 3) * 8;

  for (int k0 = 0; k0 < K; k0 += 32){
    __syncthreads();
    gload_lds16(A  + (size_t)(m0 + r0) * K + k0 + koff, sA + c0 * 512);
    gload_lds16(A  + (size_t)(m0 + r1) * K + k0 + koff, sA + c1 * 512);
    gload_lds16(Bt + (size_t)(n0 + r0) * K + k0 + koff, sB + c0 * 512);
    gload_lds16(Bt + (size_t)(n0 + r1) * K + k0 + koff, sB + c1 * 512);
    __syncthreads();
    bf16x8 af[4], bfv[4];
    #pragma unroll
    for (int mi = 0; mi < 4; ++mi) af[mi]  = *(const bf16x8*)(sA + (wr * 64 + mi * 16 + l16) * 32 + g * 8);
    #pragma unroll
    for (int ni = 0; ni < 4; ++ni) bfv[ni] = *(const bf16x8*)(sB + (wc * 64 + ni * 16 + l16) * 32 + g * 8);
    #pragma unroll
    for (int mi = 0; mi < 4; ++mi)
      #pragma unroll
      for (int ni = 0; ni < 4; ++ni)
        acc[mi][ni] = __builtin_amdgcn_mfma_f32_16x16x32_bf16(af[mi], bfv[ni], acc[mi][ni], 0, 0, 0);
  }

  #pragma unroll
  for (int ni = 0; ni < 4; ++ni){
    const int col = n0 + wc * 64 + ni * 16 + l16;
    const float bv = bias[col];
    #pragma unroll
    for (int mi = 0; mi < 4; ++mi){
      const int row = m0 + wr * 64 + mi * 16 + g * 4;
      #pragma unroll
      for (int r = 0; r < 4; ++r)
        outp[(size_t)(row + r) * N + col] = acc[mi][ni][r] + bv;
    }
  }
}

// ---------------- RoPE: shared trig per position, (d, d+40) pair processing ----------------
__global__ void k_rope(const bf16_t* __restrict__ qkv, const float* __restrict__ rope,
                       bf16_t* __restrict__ q_t, bf16_t* __restrict__ k_t){
  const int s = blockIdx.x;
  const int tid = threadIdx.x;
  __shared__ float cs_s[40], sn_s[40];
  if (tid < 40){
    float sn, cs;
    sincosf(rope[s * 40 + tid], &sn, &cs);
    cs_s[tid] = cs; sn_s[tid] = sn;
  }
  __syncthreads();
  const size_t base = (size_t)s * N3;
  const float SCALE = 0.11180339887498949f; // 1/sqrt(80)
  for (int t = tid; t < NH * 40; t += 256){
    const int h = t / 40, dm = t % 40;
    const float cs = cs_s[dm], sn = sn_s[dm];
    const int i = h * HD + dm;
    float q1 = (float)qkv[base + i];
    float q2 = (float)qkv[base + i + 40];
    float k1 = (float)qkv[base + HID + i];
    float k2 = (float)qkv[base + HID + i + 40];
    size_t o = ((size_t)h * S_LEN + s) * HDP + dm;
    q_t[o]      = (bf16_t)((q1 * cs - q2 * sn) * SCALE);
    q_t[o + 40] = (bf16_t)((q2 * cs + q1 * sn) * SCALE);
    k_t[o]      = (bf16_t)(k1 * cs - k2 * sn);
    k_t[o + 40] = (bf16_t)(k2 * cs + k1 * sn);
  }
  for (int t = tid; t < NH * 16; t += 256){
    const int h = t >> 4, d = HD + (t & 15);
    size_t o = ((size_t)h * S_LEN + s) * HDP + d;
    q_t[o] = (bf16_t)0.f;
    k_t[o] = (bf16_t)0.f;
  }
}

// ---------------- V transpose: v_T[h][d][s] = v[s][h][d] ----------------
__global__ __launch_bounds__(256) void k_vtrans(const bf16_t* __restrict__ qkv, bf16_t* __restrict__ v_T){
  const int h  = blockIdx.z;
  const int d0 = blockIdx.y * 16;
  const int s0 = blockIdx.x * 64;
  __shared__ bf16_t tile[64][17];
  const int tid = threadIdx.x;
  const int dl = tid & 15, sl = tid >> 4;
  #pragma unroll
  for (int p = 0; p < 4; ++p){
    int s = s0 + p * 16 + sl;
    tile[p * 16 + sl][dl] = qkv[(size_t)s * N3 + 2 * HID + h * HD + d0 + dl];
  }
  __syncthreads();
  const int s2 = tid & 63, d2 = tid >> 6;
  #pragma unroll
  for (int p = 0; p < 4; ++p){
    int d = p * 4 + d2;
    v_T[((size_t)h * HDP + d0 + d) * S_LEN + s0 + s2] = tile[s2][d];
  }
}

// ---------------- flash attention: cooperative LDS-staged K/V, swapped MFMA ----------------
__global__ __launch_bounds__(256) void k_attn(const bf16_t* __restrict__ q_t, const bf16_t* __restrict__ k_t,
                                              const bf16_t* __restrict__ v_T, const int* __restrict__ rlo,
                                              const int* __restrict__ rhi, bf16_t* __restrict__ attn){
  __shared__ bf16_t sLds[15872];

  const int b = blockIdx.x;
  const int xcd = b & 7, bi = b >> 3;
  const int h  = xcd * 2 + (bi & 1);
  const int qb = bi >> 1;

  const int tid = threadIdx.x;
  const int wave = tid >> 6, lane = tid & 63;
  const int g = lane >> 4, l16 = lane & 15;
  const int q0 = qb * 64 + wave * 16;
  const size_t hq = (size_t)h * S_LEN;
  const bf16_t* vbase = v_T + (size_t)h * HDP * S_LEN;

  bf16_t* myP = sLds + 11776 + wave * 1024;
  const int swz = (l16 & 7) << 3;

  int soff[6];
  #pragma unroll
  for (int i = 0; i < 6; ++i){
    int c = wave + 4 * i;
    if (c < 13){
      int p = c * 1024 + lane * 16;
      int row = p / 208, slot = (p % 208) >> 4;
      soff[i] = row * 96 + slot * 8;
    } else if (c < 23){
      int cv = c - 13;
      int row = cv * 8 + (lane >> 3);
      int scol = (lane & 7) ^ (row & 7);
      soff[i] = row * S_LEN + scol * 8;
    } else soff[i] = 0;
  }

  bf16x8 qf[3];
  #pragma unroll
  for (int c = 0; c < 3; ++c)
    qf[c] = *(const bf16x8*)(q_t + (hq + q0 + l16) * HDP + c * 32 + g * 8);

  const int my_lo = rlo[q0 + l16], my_hi = rhi[q0 + l16];
  const int w_lo = rlo[q0], w_hi = rhi[q0 + 15];
  const int lo_blk = rlo[qb * 64] & ~(KVB - 1);
  const int hi_blk = rhi[qb * 64 + 63];

  float m_run = -1e30f, l_run = 0.f;
  f32x4 acc[5] = {};

  for (int kv0 = lo_blk; kv0 < hi_blk; kv0 += KVB){
    __syncthreads();
    const bf16_t* kbase = k_t + (hq + kv0) * HDP;
    #pragma unroll
    for (int i = 0; i < 6; ++i){
      int c = wave + 4 * i;
      if (c < 13)      gload_lds16(kbase + soff[i], sLds + c * 512);
      else if (c < 23) gload_lds16(vbase + kv0 + soff[i], sLds + c * 512);
    }
    __syncthreads();

    if (kv0 + KVB > w_lo && kv0 < w_hi){
      f32x4 sc[4];
      #pragma unroll
      for (int j = 0; j < 4; ++j){
        f32x4 t = {0.f, 0.f, 0.f, 0.f};
        #pragma unroll
        for (int c = 0; c < 3; ++c){
          bf16x8 kf = *(const bf16x8*)(sLds + (j * 16 + l16) * 104 + (4 * c + g) * 8);
          t = __builtin_amdgcn_mfma_f32_16x16x32_bf16(kf, qf[c], t, 0, 0, 0);
        }
        sc[j] = t;
      }
      float p[4][4];
      float mx = -1e30f;
      #pragma unroll
      for (int j = 0; j < 4; ++j)
        #pragma unroll
        for (int r = 0; r < 4; ++r){
          int kvi = kv0 + j * 16 + g * 4 + r;
          bool ok = (kvi >= my_lo) && (kvi < my_hi);
          float sv = ok ? sc[j][r] : -1e30f;
          p[j][r] = sv;
          mx = fmaxf(mx, sv);
        }
      mx = fmaxf(mx, __shfl_xor(mx, 16));
      mx = fmaxf(mx, __shfl_xor(mx, 32));
      float mn = fmaxf(m_run, mx);
      float fr = __expf(m_run - mn);
      m_run = mn;
      float sum = 0.f;
      #pragma unroll
      for (int j = 0; j < 4; ++j)
        #pragma unroll
        for (int r = 0; r < 4; ++r){
          float pe = (p[j][r] > -1e29f) ? __expf(p[j][r] - mn) : 0.f;
          p[j][r] = pe;
          sum += pe;
        }
      sum += __shfl_xor(sum, 16);
      sum += __shfl_xor(sum, 32);
      l_run = l_run * fr + sum;
      #pragma unroll
      for (int ni = 0; ni < 5; ++ni)
        #pragma unroll
        for (int r = 0; r < 4; ++r)
          acc[ni][r] *= fr;
      #pragma unroll
      for (int j = 0; j < 4; ++j){
        bf16x4 pv;
        #pragma unroll
        for (int r = 0; r < 4; ++r) pv[r] = (bf16_t)p[j][r];
        *(bf16x4*)(myP + l16 * KVB + ((j * 16 + g * 4) ^ swz)) = pv;
      }
      bf16x8 pa0 = *(const bf16x8*)(myP + l16 * KVB + ((g * 8) ^ swz));
      bf16x8 pa1 = *(const bf16x8*)(myP + l16 * KVB + ((32 + g * 8) ^ swz));
      #pragma unroll
      for (int ni = 0; ni < 5; ++ni){
        const int d = ni * 16 + l16;
        bf16x8 vf0 = *(const bf16x8*)(sLds + 6656 + d * 64 + ((g) ^ (d & 7)) * 8);
        bf16x8 vf1 = *(const bf16x8*)(sLds + 6656 + d * 64 + ((4 + g) ^ (d & 7)) * 8);
        acc[ni] = __builtin_amdgcn_mfma_f32_16x16x32_bf16(vf0, pa0, acc[ni], 0, 0, 0);
        acc[ni] = __builtin_amdgcn_mfma_f32_16x16x32_bf16(vf1, pa1, acc[ni], 0, 0, 0);
      }
    }
  }
  const float inv = 1.f / l_run;
  #pragma unroll
  for (int ni = 0; ni < 5; ++ni)
    #pragma unroll
    for (int r = 0; r < 4; ++r)
      attn[(size_t)(q0 + l16) * HID + h * HD + ni * 16 + g * 4 + r] = (bf16_t)(acc[ni][r] * inv);
}

// ---------------- launch ----------------

extern "C" void kernel_launch(void* const* d_in, const int* in_sizes, int n_in,
                              void* d_out, int out_size, void* d_ws, size_t ws_size,
                              hipStream_t stream){
  const float* x    = (const float*)d_in[0];
  const float* rope = (const float*)d_in[1];
  const int*   cu   = (const int*)  d_in[2];
  const float* wqkv = (const float*)d_in[3];
  const float* bqkv = (const float*)d_in[4];
  const float* wo   = (const float*)d_in[5];
  const float* bo   = (const float*)d_in[6];
  float* out = (float*)d_out;

  char* ws = (char*)d_ws;
  size_t off = 0;
  auto alloc = [&](size_t bytes) -> void* {
    void* p = ws + off;
    off += (bytes + 255) & ~(size_t)255;
    return p;
  };
  bf16_t* x_bf   = (bf16_t*)alloc((size_t)S_LEN * HID * 2);
  bf16_t* w_t    = (bf16_t*)alloc((size_t)N3 * HID * 2);
  bf16_t* wo_t   = (bf16_t*)alloc((size_t)HID * HID * 2);
  bf16_t* qkv_bf = (bf16_t*)alloc((size_t)S_LEN * N3 * 2);
  bf16_t* q_t    = (bf16_t*)alloc((size_t)NH * S_LEN * HDP * 2);
  bf16_t* k_t    = (bf16_t*)alloc((size_t)NH * S_LEN * HDP * 2);
  bf16_t* v_T    = (bf16_t*)alloc((size_t)NH * HDP * S_LEN * 2);
  int* seg = (int*)alloc(S_LEN * 4);
  int* rlo = (int*)alloc(S_LEN * 4);
  int* rhi = (int*)alloc(S_LEN * 4);
  bf16_t* attn_bf = x_bf;  // alias: x_bf dead after QKV GEMM

  k_f2bf<<<1024, 256, 0, stream>>>(x, x_bf, S_LEN * HID / 4);
  k_transpose_bf<<<dim3(N3 / 64, HID / 64), 256, 0, stream>>>(wqkv, w_t, HID, N3);
  k_transpose_bf<<<dim3(HID / 64, HID / 64), 256, 0, stream>>>(wo, wo_t, HID, HID);
  k_seg<<<16, 256, 0, stream>>>(cu, seg, rlo, rhi);

  // QKV: M=4096, N=3840, K=1280 -> grid 15*16 = 240 blocks (240%8==0 -> simple XCD swizzle)
  k_gemm256<<<(N3 / 256) * (S_LEN / 256), 512, 0, stream>>>(x_bf, w_t, bqkv, qkv_bf, S_LEN, N3, HID, N3 / 256);

  k_rope<<<S_LEN, 256, 0, stream>>>(qkv_bf, rope, q_t, k_t);
  k_vtrans<<<dim3(S_LEN / 64, 5, NH), 256, 0, stream>>>(qkv_bf, v_T);

  k_attn<<<1024, 256, 0, stream>>>(q_t, k_t, v_T, rlo, rhi, attn_bf);

  k_gemm<<<dim3(HID / 128, S_LEN / 128), 256, 0, stream>>>(attn_bf, wo_t, bo, out, S_LEN, HID, HID);
}

// Round 6
// 166.466 us; speedup vs baseline: 2.2283x; 1.1106x over previous
//
#include <hip/hip_runtime.h>
#include <hip/hip_bf16.h>
#include <math.h>

#define S_LEN 4096
#define HID   1280
#define NH    16
#define HD    80
#define HDP   96
#define N3    3840
#define KVB   128

typedef __bf16 bf16_t;
typedef __bf16 bf16x4 __attribute__((ext_vector_type(4)));
typedef __bf16 bf16x8 __attribute__((ext_vector_type(8)));
typedef float  f32x4  __attribute__((ext_vector_type(4)));

__device__ inline void gload_lds16(const bf16_t* g, const bf16_t* lds_base){
  __builtin_amdgcn_global_load_lds((const __attribute__((address_space(1))) void*)g,
                                   (__attribute__((address_space(3))) void*)lds_base,
                                   16, 0, 0);
}

__device__ inline float exp2fast(float x){
#if __has_builtin(__builtin_amdgcn_exp2f)
  return __builtin_amdgcn_exp2f(x);
#else
  return __expf(x * 0.69314718055994531f);
#endif
}

// ---------------- prep kernels ----------------

__global__ void k_f2bf(const float* __restrict__ in, bf16_t* __restrict__ out, int n4){
  int i = blockIdx.x * blockDim.x + threadIdx.x;
  int stride = gridDim.x * blockDim.x;
  for (; i < n4; i += stride){
    float4 v = ((const float4*)in)[i];
    bf16x4 o;
    o[0] = (bf16_t)v.x; o[1] = (bf16_t)v.y; o[2] = (bf16_t)v.z; o[3] = (bf16_t)v.w;
    ((bf16x4*)out)[i] = o;
  }
}

// in: K x N f32 row-major -> out: N x K bf16 row-major, 64x64 LDS tiles
__global__ __launch_bounds__(256) void k_transpose_bf(const float* __restrict__ in, bf16_t* __restrict__ out,
                                                      int K, int N){
  __shared__ bf16_t tile[64][65];
  const int tid = threadIdx.x;
  const int n0 = blockIdx.x * 64, k0 = blockIdx.y * 64;
  const int ln = tid & 63, w = tid >> 6;
  #pragma unroll
  for (int p = 0; p < 16; ++p){
    int k = w + p * 4;
    tile[k][ln] = (bf16_t)in[(size_t)(k0 + k) * N + n0 + ln];
  }
  __syncthreads();
  const int lk = tid & 63;
  #pragma unroll
  for (int p = 0; p < 16; ++p){
    int n = w + p * 4;
    out[(size_t)(n0 + n) * K + k0 + lk] = tile[lk][n];
  }
}

__global__ void k_seg(const int* __restrict__ cu, int* __restrict__ seg,
                      int* __restrict__ rlo, int* __restrict__ rhi){
  int s = blockIdx.x * blockDim.x + threadIdx.x;
  if (s >= S_LEN) return;
  int c = 0;
  #pragma unroll
  for (int j = 0; j < 9; ++j) c += (cu[j] <= s) ? 1 : 0;
  seg[s] = c;
  rlo[s] = cu[c - 1];
  rhi[s] = cu[c];
}

// ---------------- 256x256 8-wave deep-pipelined GEMM (QKV), bf16 out ----------------
__global__ __launch_bounds__(512, 2) void k_gemm256(const bf16_t* __restrict__ A, const bf16_t* __restrict__ Bt,
                                                    const float* __restrict__ bias, bf16_t* __restrict__ outp,
                                                    int M, int N, int K, int nbn){
  __shared__ bf16_t lds[32768];
  const int tid = threadIdx.x;
  const int wv = tid >> 6, lane = tid & 63;
  const int waveM = wv >> 2, waveN = wv & 3;
  const int g = lane >> 4, l16 = lane & 15;

  const int cpx = gridDim.x >> 3;
  const int bswz = ((int)blockIdx.x & 7) * cpx + ((int)blockIdx.x >> 3);
  const int m0 = (bswz / nbn) * 256, n0 = (bswz % nbn) * 256;

  int srow[2], scol[2];
  #pragma unroll
  for (int i = 0; i < 2; ++i){
    int c = wv + 8 * i;
    int prow = c * 8 + (lane >> 3);
    int inner = (lane & 7) ^ (lane >> 3);
    srow[i] = prow * 2 + (inner >> 2);
    scol[i] = (inner & 3) * 8;
  }

  const int swzh = (l16 >> 1) & 7;
  const int rcol = ((((l16 & 1) << 2) + g) ^ swzh) * 8;
  int aoff[8], boff[4];
  #pragma unroll
  for (int mi = 0; mi < 8; ++mi)
    aoff[mi] = (waveM * 64 + mi * 8 + (l16 >> 1)) * 64 + rcol;
  #pragma unroll
  for (int ni = 0; ni < 4; ++ni)
    boff[ni] = (waveN * 32 + ni * 8 + (l16 >> 1)) * 64 + rcol;

  f32x4 acc[8][4] = {};
  const int NT = K / 32;

  auto stage = [&](int t, int bb){
    const int kc = t * 32;
    #pragma unroll
    for (int i = 0; i < 2; ++i)
      gload_lds16(A + (size_t)(m0 + srow[i]) * K + kc + scol[i], lds + bb * 16384 + (wv + 8 * i) * 512);
    #pragma unroll
    for (int i = 0; i < 2; ++i)
      gload_lds16(Bt + (size_t)(n0 + srow[i]) * K + kc + scol[i], lds + bb * 16384 + 8192 + (wv + 8 * i) * 512);
  };

  stage(0, 0);
  int cur = 0;
  for (int t = 0; t < NT; ++t){
    if (t + 1 < NT){
      stage(t + 1, cur ^ 1);
      asm volatile("s_waitcnt vmcnt(4)" ::: "memory");
    } else {
      asm volatile("s_waitcnt vmcnt(0)" ::: "memory");
    }
    asm volatile("s_barrier" ::: "memory");

    const bf16_t* Ab = lds + cur * 16384;
    const bf16_t* Bb = Ab + 8192;
    bf16x8 bfv[4], af[4];
    #pragma unroll
    for (int ni = 0; ni < 4; ++ni) bfv[ni] = *(const bf16x8*)(Bb + boff[ni]);
    #pragma unroll
    for (int mi = 0; mi < 4; ++mi) af[mi] = *(const bf16x8*)(Ab + aoff[mi]);
    __builtin_amdgcn_s_setprio(1);
    #pragma unroll
    for (int mi = 0; mi < 4; ++mi)
      #pragma unroll
      for (int ni = 0; ni < 4; ++ni)
        acc[mi][ni] = __builtin_amdgcn_mfma_f32_16x16x32_bf16(af[mi], bfv[ni], acc[mi][ni], 0, 0, 0);
    __builtin_amdgcn_s_setprio(0);
    asm volatile("s_barrier" ::: "memory");

    #pragma unroll
    for (int mi = 0; mi < 4; ++mi) af[mi] = *(const bf16x8*)(Ab + aoff[4 + mi]);
    __builtin_amdgcn_s_setprio(1);
    #pragma unroll
    for (int mi = 0; mi < 4; ++mi)
      #pragma unroll
      for (int ni = 0; ni < 4; ++ni)
        acc[4 + mi][ni] = __builtin_amdgcn_mfma_f32_16x16x32_bf16(af[mi], bfv[ni], acc[4 + mi][ni], 0, 0, 0);
    __builtin_amdgcn_s_setprio(0);
    asm volatile("s_barrier" ::: "memory");
    cur ^= 1;
  }

  #pragma unroll
  for (int ni = 0; ni < 4; ++ni){
    const int col = n0 + waveN * 64 + ni * 16 + l16;
    const float bv = bias[col];
    #pragma unroll
    for (int mi = 0; mi < 8; ++mi){
      const int row = m0 + waveM * 128 + mi * 16 + g * 4;
      #pragma unroll
      for (int r = 0; r < 4; ++r)
        outp[(size_t)(row + r) * N + col] = (bf16_t)(acc[mi][ni][r] + bv);
    }
  }
}

// ---------------- 128x64 4-wave deep-pipelined GEMM (proj), f32 out ----------------
__global__ __launch_bounds__(256, 4) void k_gemm_dp(const bf16_t* __restrict__ A, const bf16_t* __restrict__ Bt,
                                                    const float* __restrict__ bias, float* __restrict__ outp,
                                                    int M, int N, int K, int nbn){
  // per buf: A 128x32 (4096 el) + B 64x32 (2048 el) = 6144 el; dbuf 12288 el (24.5 KB)
  __shared__ bf16_t lds[12288];
  const int tid = threadIdx.x;
  const int wv = tid >> 6, lane = tid & 63;
  const int wr = wv >> 1, wc = wv & 1;
  const int g = lane >> 4, l16 = lane & 15;

  const int cpx = gridDim.x >> 3;
  const int bswz = ((int)blockIdx.x & 7) * cpx + ((int)blockIdx.x >> 3);
  const int m0 = (bswz / nbn) * 128, n0 = (bswz % nbn) * 64;

  int srow_[3], scol_[3];
  #pragma unroll
  for (int i = 0; i < 3; ++i){
    int c = wv + 4 * i;                 // 0..11: A chunks 0-7, B chunks 8-11
    int lc = (c < 8) ? c : c - 8;
    int prow = lc * 8 + (lane >> 3);
    int inner = (lane & 7) ^ (lane >> 3);
    srow_[i] = prow * 2 + (inner >> 2);
    scol_[i] = (inner & 3) * 8;
  }

  const int swzh = (l16 >> 1) & 7;
  const int rcol = ((((l16 & 1) << 2) + g) ^ swzh) * 8;
  int aoff[4], boff[2];
  #pragma unroll
  for (int mi = 0; mi < 4; ++mi)
    aoff[mi] = (wr * 32 + mi * 8 + (l16 >> 1)) * 64 + rcol;
  #pragma unroll
  for (int ni = 0; ni < 2; ++ni)
    boff[ni] = (wc * 16 + ni * 8 + (l16 >> 1)) * 64 + rcol;

  f32x4 acc[4][2] = {};
  const int NT = K / 32;

  auto stage = [&](int t, int bb){
    const int kc = t * 32;
    #pragma unroll
    for (int i = 0; i < 3; ++i){
      int c = wv + 4 * i;
      if (c < 8) gload_lds16(A  + (size_t)(m0 + srow_[i]) * K + kc + scol_[i], lds + bb * 6144 + c * 512);
      else       gload_lds16(Bt + (size_t)(n0 + srow_[i]) * K + kc + scol_[i], lds + bb * 6144 + 4096 + (c - 8) * 512);
    }
  };

  stage(0, 0);
  int cur = 0;
  for (int t = 0; t < NT; ++t){
    if (t + 1 < NT){
      stage(t + 1, cur ^ 1);
      asm volatile("s_waitcnt vmcnt(3)" ::: "memory");
    } else {
      asm volatile("s_waitcnt vmcnt(0)" ::: "memory");
    }
    asm volatile("s_barrier" ::: "memory");

    const bf16_t* Ab = lds + cur * 6144;
    const bf16_t* Bb = Ab + 4096;
    bf16x8 af[4], bfv[2];
    #pragma unroll
    for (int ni = 0; ni < 2; ++ni) bfv[ni] = *(const bf16x8*)(Bb + boff[ni]);
    #pragma unroll
    for (int mi = 0; mi < 4; ++mi) af[mi] = *(const bf16x8*)(Ab + aoff[mi]);
    __builtin_amdgcn_s_setprio(1);
    #pragma unroll
    for (int mi = 0; mi < 4; ++mi)
      #pragma unroll
      for (int ni = 0; ni < 2; ++ni)
        acc[mi][ni] = __builtin_amdgcn_mfma_f32_16x16x32_bf16(af[mi], bfv[ni], acc[mi][ni], 0, 0, 0);
    __builtin_amdgcn_s_setprio(0);
    asm volatile("s_barrier" ::: "memory");
    cur ^= 1;
  }

  #pragma unroll
  for (int ni = 0; ni < 2; ++ni){
    const int col = n0 + wc * 32 + ni * 16 + l16;
    const float bv = bias[col];
    #pragma unroll
    for (int mi = 0; mi < 4; ++mi){
      const int row = m0 + wr * 64 + mi * 16 + g * 4;
      #pragma unroll
      for (int r = 0; r < 4; ++r)
        outp[(size_t)(row + r) * N + col] = acc[mi][ni][r] + bv;
    }
  }
}

// ---------------- RoPE (q pre-scaled by log2e/sqrt(HD) for exp2-domain softmax) ----------------
__global__ void k_rope(const bf16_t* __restrict__ qkv, const float* __restrict__ rope,
                       bf16_t* __restrict__ q_t, bf16_t* __restrict__ k_t){
  const int s = blockIdx.x;
  const int tid = threadIdx.x;
  __shared__ float cs_s[40], sn_s[40];
  if (tid < 40){
    float sn, cs;
    sincosf(rope[s * 40 + tid], &sn, &cs);
    cs_s[tid] = cs; sn_s[tid] = sn;
  }
  __syncthreads();
  const size_t base = (size_t)s * N3;
  const float SCALE = 0.11180339887498949f * 1.4426950408889634f; // 1/sqrt(80) * log2(e)
  for (int t = tid; t < NH * 40; t += 256){
    const int h = t / 40, dm = t % 40;
    const float cs = cs_s[dm], sn = sn_s[dm];
    const int i = h * HD + dm;
    float q1 = (float)qkv[base + i];
    float q2 = (float)qkv[base + i + 40];
    float k1 = (float)qkv[base + HID + i];
    float k2 = (float)qkv[base + HID + i + 40];
    size_t o = ((size_t)h * S_LEN + s) * HDP + dm;
    q_t[o]      = (bf16_t)((q1 * cs - q2 * sn) * SCALE);
    q_t[o + 40] = (bf16_t)((q2 * cs + q1 * sn) * SCALE);
    k_t[o]      = (bf16_t)(k1 * cs - k2 * sn);
    k_t[o + 40] = (bf16_t)(k2 * cs + k1 * sn);
  }
  for (int t = tid; t < NH * 16; t += 256){
    const int h = t >> 4, d = HD + (t & 15);
    size_t o = ((size_t)h * S_LEN + s) * HDP + d;
    q_t[o] = (bf16_t)0.f;
    k_t[o] = (bf16_t)0.f;
  }
}

// ---------------- V transpose: v_T[h][d][s] = v[s][h][d] ----------------
__global__ __launch_bounds__(256) void k_vtrans(const bf16_t* __restrict__ qkv, bf16_t* __restrict__ v_T){
  const int h  = blockIdx.z;
  const int d0 = blockIdx.y * 16;
  const int s0 = blockIdx.x * 64;
  __shared__ bf16_t tile[64][17];
  const int tid = threadIdx.x;
  const int dl = tid & 15, sl = tid >> 4;
  #pragma unroll
  for (int p = 0; p < 4; ++p){
    int s = s0 + p * 16 + sl;
    tile[p * 16 + sl][dl] = qkv[(size_t)s * N3 + 2 * HID + h * HD + d0 + dl];
  }
  __syncthreads();
  const int s2 = tid & 63, d2 = tid >> 6;
  #pragma unroll
  for (int p = 0; p < 4; ++p){
    int d = p * 4 + d2;
    v_T[((size_t)h * HDP + d0 + d) * S_LEN + s0 + s2] = tile[s2][d];
  }
}

// ---------------- flash attention: KVB=128, fast-path mask, defer-rescale, exp2 domain ----------------
// LDS: K [128 rows x 208B] @0; V [80 rows x 256B, src-swizzled granules] @26624B;
//      P per wave [16 x 152 elems] @47104B.  Total 66560 B -> 2 blocks/CU.
__global__ __launch_bounds__(256, 2) void k_attn(const bf16_t* __restrict__ q_t, const bf16_t* __restrict__ k_t,
                                                 const bf16_t* __restrict__ v_T, const int* __restrict__ rlo,
                                                 const int* __restrict__ rhi, bf16_t* __restrict__ attn){
  __shared__ bf16_t sLds[33280];

  const int b = blockIdx.x;
  const int xcd = b & 7, bi = b >> 3;
  const int h  = xcd * 2 + (bi & 1);
  const int qb = bi >> 1;

  const int tid = threadIdx.x;
  const int wave = tid >> 6, lane = tid & 63;
  const int g = lane >> 4, l16 = lane & 15;
  const int q0 = qb * 64 + wave * 16;
  const size_t hq = (size_t)h * S_LEN;
  const bf16_t* vbase = v_T + (size_t)h * HDP * S_LEN;

  bf16_t* pbase = sLds + 23552 + wave * 2432;

  // staging precompute: 46 chunks of 1024B (K 0-25, V 26-45); wave w takes c = w+4i.
  const int nchunk = (wave < 2) ? 12 : 11;
  int soff[12];
  #pragma unroll
  for (int i = 0; i < 12; ++i){
    int c = wave + 4 * i;
    if (c < 26){
      int p = c * 1024 + lane * 16;
      int row = p / 208, slot = (p % 208) >> 4;
      soff[i] = row * 96 + slot * 8;        // slot 12 overruns 16B into next row: benign, never read
    } else if (c < 46){
      int cv = c - 26;
      int row = cv * 4 + (lane >> 4);
      int s = (lane & 15) ^ (row & 7);      // XOR low-3 bits of granule; bit3 preserved
      soff[i] = row * S_LEN + s * 8;
    } else soff[i] = 0;
  }

  bf16x8 qf[3];
  #pragma unroll
  for (int c = 0; c < 3; ++c)
    qf[c] = *(const bf16x8*)(q_t + (hq + q0 + l16) * HDP + c * 32 + g * 8);

  const int my_lo = rlo[q0 + l16], my_hi = rhi[q0 + l16];
  const int w_lo = rlo[q0], w_hi = rhi[q0 + 15];
  const int flo = rlo[q0 + 15], fhi = rhi[q0];          // fast-path bounds (rows sorted)
  const int lo_blk = rlo[qb * 64] & ~(KVB - 1);
  const int hi_blk = rhi[qb * 64 + 63];

  float m_run = -30.f, l_run = 0.f;   // -30 floor: exact by softmax shift-invariance
  f32x4 acc[5] = {};

  for (int kv0 = lo_blk; kv0 < hi_blk; kv0 += KVB){
    __syncthreads();
    const bf16_t* kb = k_t + (hq + kv0) * HDP;
    const bf16_t* vb = vbase + kv0;
    #pragma unroll
    for (int i = 0; i < 12; ++i){
      if (i < nchunk){
        int c = wave + 4 * i;
        if (c < 26) gload_lds16(kb + soff[i], sLds + c * 512);
        else        gload_lds16(vb + soff[i], sLds + 13312 + (c - 26) * 512);
      }
    }
    __syncthreads();

    if (kv0 + KVB <= w_lo || kv0 >= w_hi) continue;

    // QK^T (swapped): lane holds scores for q=q0+l16 at kv = kv0 + j*16 + g*4 + r
    f32x4 sc[8];
    #pragma unroll
    for (int j = 0; j < 8; ++j){
      f32x4 t = {0.f, 0.f, 0.f, 0.f};
      #pragma unroll
      for (int c = 0; c < 3; ++c){
        bf16x8 kf = *(const bf16x8*)(sLds + (j * 16 + l16) * 104 + (4 * c + g) * 8);
        t = __builtin_amdgcn_mfma_f32_16x16x32_bf16(kf, qf[c], t, 0, 0, 0);
      }
      sc[j] = t;
    }

    if (!(kv0 >= flo && kv0 + KVB <= fhi)){    // boundary tile: mask
      #pragma unroll
      for (int j = 0; j < 8; ++j)
        #pragma unroll
        for (int r = 0; r < 4; ++r){
          int kvi = kv0 + j * 16 + g * 4 + r;
          if (kvi < my_lo || kvi >= my_hi) sc[j][r] = -1e30f;
        }
    }

    float mx = fmaxf(fmaxf(sc[0][0], sc[0][1]), fmaxf(sc[0][2], sc[0][3]));
    #pragma unroll
    for (int j = 1; j < 8; ++j)
      mx = fmaxf(mx, fmaxf(fmaxf(sc[j][0], sc[j][1]), fmaxf(sc[j][2], sc[j][3])));
    mx = fmaxf(mx, __shfl_xor(mx, 16));
    mx = fmaxf(mx, __shfl_xor(mx, 32));

    if (!__all(mx <= m_run + 8.0f)){           // T13 defer-rescale
      float mn = fmaxf(m_run, mx);
      float fr = exp2fast(m_run - mn);
      m_run = mn;
      l_run *= fr;
      #pragma unroll
      for (int ni = 0; ni < 5; ++ni)
        #pragma unroll
        for (int r = 0; r < 4; ++r)
          acc[ni][r] *= fr;
    }

    float sum = 0.f;
    #pragma unroll
    for (int j = 0; j < 8; ++j){
      bf16x4 pv;
      #pragma unroll
      for (int r = 0; r < 4; ++r){
        float pe = exp2fast(sc[j][r] - m_run);  // masked -> underflow to exact 0
        sum += pe;
        pv[r] = (bf16_t)pe;
      }
      *(bf16x4*)(pbase + l16 * 152 + j * 16 + g * 4) = pv;
    }
    sum += __shfl_xor(sum, 16);
    sum += __shfl_xor(sum, 32);
    l_run += sum;

    bf16x8 pa[4];
    #pragma unroll
    for (int ks = 0; ks < 4; ++ks)
      pa[ks] = *(const bf16x8*)(pbase + l16 * 152 + ks * 32 + g * 8);
    #pragma unroll
    for (int ni = 0; ni < 5; ++ni){
      const int d = ni * 16 + l16;
      #pragma unroll
      for (int ks = 0; ks < 4; ++ks){
        bf16x8 vf = *(const bf16x8*)(sLds + 13312 + d * 128 + (((4 * ks + g) ^ (d & 7)) * 8));
        acc[ni] = __builtin_amdgcn_mfma_f32_16x16x32_bf16(vf, pa[ks], acc[ni], 0, 0, 0);
      }
    }
  }

  const float inv = 1.f / l_run;
  #pragma unroll
  for (int ni = 0; ni < 5; ++ni)
    #pragma unroll
    for (int r = 0; r < 4; ++r)
      attn[(size_t)(q0 + l16) * HID + h * HD + ni * 16 + g * 4 + r] = (bf16_t)(acc[ni][r] * inv);
}

// ---------------- launch ----------------

extern "C" void kernel_launch(void* const* d_in, const int* in_sizes, int n_in,
                              void* d_out, int out_size, void* d_ws, size_t ws_size,
                              hipStream_t stream){
  const float* x    = (const float*)d_in[0];
  const float* rope = (const float*)d_in[1];
  const int*   cu   = (const int*)  d_in[2];
  const float* wqkv = (const float*)d_in[3];
  const float* bqkv = (const float*)d_in[4];
  const float* wo   = (const float*)d_in[5];
  const float* bo   = (const float*)d_in[6];
  float* out = (float*)d_out;

  char* ws = (char*)d_ws;
  size_t off = 0;
  auto alloc = [&](size_t bytes) -> void* {
    void* p = ws + off;
    off += (bytes + 255) & ~(size_t)255;
    return p;
  };
  bf16_t* x_bf   = (bf16_t*)alloc((size_t)S_LEN * HID * 2);
  bf16_t* w_t    = (bf16_t*)alloc((size_t)N3 * HID * 2);
  bf16_t* wo_t   = (bf16_t*)alloc((size_t)HID * HID * 2);
  bf16_t* qkv_bf = (bf16_t*)alloc((size_t)S_LEN * N3 * 2);
  bf16_t* q_t    = (bf16_t*)alloc((size_t)NH * S_LEN * HDP * 2);
  bf16_t* k_t    = (bf16_t*)alloc((size_t)NH * S_LEN * HDP * 2);
  bf16_t* v_T    = (bf16_t*)alloc((size_t)NH * HDP * S_LEN * 2);
  int* seg = (int*)alloc(S_LEN * 4);
  int* rlo = (int*)alloc(S_LEN * 4);
  int* rhi = (int*)alloc(S_LEN * 4);
  bf16_t* attn_bf = x_bf;  // alias: x_bf dead after QKV GEMM

  k_f2bf<<<1024, 256, 0, stream>>>(x, x_bf, S_LEN * HID / 4);
  k_transpose_bf<<<dim3(N3 / 64, HID / 64), 256, 0, stream>>>(wqkv, w_t, HID, N3);
  k_transpose_bf<<<dim3(HID / 64, HID / 64), 256, 0, stream>>>(wo, wo_t, HID, HID);
  k_seg<<<16, 256, 0, stream>>>(cu, seg, rlo, rhi);

  // QKV: grid 15*16 = 240 (240%8==0)
  k_gemm256<<<(N3 / 256) * (S_LEN / 256), 512, 0, stream>>>(x_bf, w_t, bqkv, qkv_bf, S_LEN, N3, HID, N3 / 256);

  k_rope<<<S_LEN, 256, 0, stream>>>(qkv_bf, rope, q_t, k_t);
  k_vtrans<<<dim3(S_LEN / 64, 5, NH), 256, 0, stream>>>(qkv_bf, v_T);

  k_attn<<<1024, 256, 0, stream>>>(q_t, k_t, v_T, rlo, rhi, attn_bf);

  // proj: grid 32*20 = 640 (640%8==0)
  k_gemm_dp<<<(S_LEN / 128) * (HID / 64), 256, 0, stream>>>(attn_bf, wo_t, bo, out, S_LEN, HID, HID, HID / 64);
}